// Round 5
// baseline (2735.896 us; speedup 1.0000x reference)
//
#include <hip/hip_runtime.h>
#include <hip/hip_bf16.h>

#define NN 30000
#define NE 480000
#define NH 4
#define DH 64
#define MF 30
#define KG 10
#define RATIO 0.18257418583505536f   /* 1/sqrt(30) */
#define DNRM  0.35355339059327373f   /* 64^-0.25  */

// fp32 params block layout (element offsets)
#define P_WF    0        /* [768][256] Wq|Wk|Wv rows */
#define P_BF    196608   /* [768] bq|bk|bv */
#define P_WOF   197376   /* [64][256] Wo */
#define P_WOBF  213760   /* [64] Wo bias */
#define P_BBF   213824   /* [4] rb bias b */
#define P_PROJ  213828   /* [30][64] proj */
#define P_TAU   215748   /* scalar */
#define P_TOTAL 215749

typedef unsigned short u16;
typedef unsigned int   u32;

__device__ __forceinline__ float u2f(u16 u) { return __uint_as_float(((u32)u) << 16); }
// order-preserving float->uint encoding for atomicMax over signed floats
__device__ __forceinline__ u32  encf(float f) { u32 u = __float_as_uint(f); return (u & 0x80000000u) ? ~u : (u | 0x80000000u); }
__device__ __forceinline__ float decf(u32 u)  { return (u & 0x80000000u) ? __uint_as_float(u & 0x7FFFFFFFu) : __uint_as_float(~u); }

// ---------------- dtype detection (fp32 vs bf16 input tensors) ----------------
// Round-3 result: fires flag=1 on this harness (inputs are fp32, matching the
// reference's declared float32). Kept as a cheap guard.
__global__ void k_detect(const u16* __restrict__ z, int* __restrict__ flag) {
    if (threadIdx.x == 0 && blockIdx.x == 0) {
        int bad = 0;
        for (int i = 0; i < 256; i += 2) {
            u16 u = z[i];
            int e = (u >> 7) & 0xFF;
            if (u != 0 && !(e >= 100 && e <= 140)) bad++;
        }
        *flag = (bad > 16) ? 1 : 0;   // 1 = inputs are fp32
    }
}

// ---------------- stage all small params to fp32 ----------------
__global__ __launch_bounds__(256) void k_cvt_params(
    const void* Wq, const void* Wk, const void* Wv,
    const void* bq, const void* bk, const void* bv,
    const void* Wo, const void* Wob, const void* bb, const void* proj,
    const void* taup, float* __restrict__ params, const int* __restrict__ flag)
{
    int i = blockIdx.x * 256 + threadIdx.x;
    if (i >= P_TOTAL) return;
    int f = *flag;
    if (i == P_TAU) {
        float v = f ? ((const float*)taup)[0] : u2f(((const u16*)taup)[0]);
        if (!(v > 1e-6f && v < 1e6f)) {  // mixed-dtype defense for the 0-d scalar
            float ff = ((const float*)taup)[0];
            v = (ff > 1e-6f && ff < 1e6f) ? ff : 0.25f;
        }
        params[i] = v;
        return;
    }
    const void* src; int j;
    if      (i < 65536)  { src = Wq;  j = i; }
    else if (i < 131072) { src = Wk;  j = i - 65536; }
    else if (i < 196608) { src = Wv;  j = i - 131072; }
    else if (i < 196864) { src = bq;  j = i - 196608; }
    else if (i < 197120) { src = bk;  j = i - 196864; }
    else if (i < 197376) { src = bv;  j = i - 197120; }
    else if (i < 213760) { src = Wo;  j = i - 197376; }
    else if (i < 213824) { src = Wob; j = i - 213760; }
    else if (i < 213828) { src = bb;  j = i - 213824; }
    else                 { src = proj; j = i - P_PROJ; }
    params[i] = f ? ((const float*)src)[j] : u2f(((const u16*)src)[j]);
}

// ---------------- degrees ----------------
__global__ __launch_bounds__(256) void k_deg(const int* __restrict__ ei, int* __restrict__ din, int* __restrict__ dout) {
    int e = blockIdx.x * 256 + threadIdx.x;
    if (e >= NE) return;
    atomicAdd(&dout[ei[e]], 1);
    atomicAdd(&din[ei[NE + e]], 1);
}

// ---------------- scan-free CSR offsets ----------------
__global__ __launch_bounds__(256) void k_off(const int* __restrict__ din, int* __restrict__ offn, int* __restrict__ counter) {
    __shared__ int s[256];
    __shared__ int base;
    int tid = threadIdx.x;
    int n = blockIdx.x * 256 + tid;
    int v = (n < NN) ? din[n] : 0;
    s[tid] = v;
    __syncthreads();
    for (int o = 1; o < 256; o <<= 1) {
        int t = (tid >= o) ? s[tid - o] : 0;
        __syncthreads();
        s[tid] += t;
        __syncthreads();
    }
    if (tid == 255) base = atomicAdd(counter, s[255]);
    __syncthreads();
    if (n < NN) offn[n] = base + s[tid] - v;
}

__global__ __launch_bounds__(256) void k_fill(const int* __restrict__ ei, const int* __restrict__ offn,
                                              int* __restrict__ fill, int* __restrict__ csr) {
    int e = blockIdx.x * 256 + threadIdx.x;
    if (e >= NE) return;
    int s = ei[e], t = ei[NE + e];
    int pos = offn[t] + atomicAdd(&fill[t], 1);
    csr[pos] = s;
}

// ---------------- fused QKV GEMM + Performer feature epilogue ----------------
// grid (ceil(NN/64), 12): y 0..3 -> Q head y; y 4..7 -> K head y-4; y 8..11 -> V cols
__global__ __launch_bounds__(256) void k_gemm_feat(
    const void* __restrict__ zv, const float* __restrict__ params, const int* __restrict__ flag,
    float* __restrict__ Vbuf, float* __restrict__ qp,
    float* __restrict__ dashK, float* __restrict__ diagK, u32* __restrict__ stab)
{
    __shared__ float smem[4160 + 1920];   // As(32x65)|Bs(32x65) -> reused as tile(64x65); + projL
    __shared__ u32 smaxL;
    float (*As)[65]   = (float(*)[65])smem;
    float (*Bs)[65]   = (float(*)[65])(smem + 2080);
    float (*tile)[65] = (float(*)[65])smem;
    float* projL      = smem + 4160;

    const float* Wf = params + P_WF;
    const float* bf = params + P_BF;
    const int f32 = *flag;
    const int tid = threadIdx.x;
    const int bm = blockIdx.x * 64;
    const int bn = blockIdx.y * 64;

    if (bn < 512) {   // Q or K block: stage proj
        for (int i = tid; i < MF * DH; i += 256) projL[i] = params[P_PROJ + i];
    }
    if (tid == 0) smaxL = 0u;

    const int lm = tid >> 2;          // 0..63
    const int lk = (tid & 3) * 8;     // 0,8,16,24
    const int tm = (tid >> 4) * 4;
    const int tn = (tid & 15) * 4;
    float acc[4][4] = {};

    for (int k0 = 0; k0 < 256; k0 += 32) {
        __syncthreads();
        int row = bm + lm;
        float e[8] = {0.f, 0.f, 0.f, 0.f, 0.f, 0.f, 0.f, 0.f};
        if (row < NN) {
            if (f32) {
                const float4* zp = (const float4*)((const float*)zv + (size_t)row * 256 + k0 + lk);
                float4 a = zp[0], c = zp[1];
                e[0] = a.x; e[1] = a.y; e[2] = a.z; e[3] = a.w;
                e[4] = c.x; e[5] = c.y; e[6] = c.z; e[7] = c.w;
            } else {
                uint4 av = *(const uint4*)((const u16*)zv + (size_t)row * 256 + k0 + lk);
                e[0] = __uint_as_float(av.x << 16); e[1] = __uint_as_float(av.x & 0xFFFF0000u);
                e[2] = __uint_as_float(av.y << 16); e[3] = __uint_as_float(av.y & 0xFFFF0000u);
                e[4] = __uint_as_float(av.z << 16); e[5] = __uint_as_float(av.z & 0xFFFF0000u);
                e[6] = __uint_as_float(av.w << 16); e[7] = __uint_as_float(av.w & 0xFFFF0000u);
            }
        }
        #pragma unroll
        for (int j = 0; j < 8; ++j) As[lk + j][lm] = e[j];
        const float4* wr = (const float4*)(Wf + (size_t)(bn + lm) * 256 + k0 + lk);
        float4 b0 = wr[0], b1 = wr[1];
        Bs[lk + 0][lm] = b0.x; Bs[lk + 1][lm] = b0.y; Bs[lk + 2][lm] = b0.z; Bs[lk + 3][lm] = b0.w;
        Bs[lk + 4][lm] = b1.x; Bs[lk + 5][lm] = b1.y; Bs[lk + 6][lm] = b1.z; Bs[lk + 7][lm] = b1.w;
        __syncthreads();
        #pragma unroll
        for (int kk = 0; kk < 32; ++kk) {
            float a0 = As[kk][tm + 0], a1 = As[kk][tm + 1], a2 = As[kk][tm + 2], a3 = As[kk][tm + 3];
            float b0v = Bs[kk][tn + 0], b1v = Bs[kk][tn + 1], b2v = Bs[kk][tn + 2], b3v = Bs[kk][tn + 3];
            acc[0][0] += a0 * b0v; acc[0][1] += a0 * b1v; acc[0][2] += a0 * b2v; acc[0][3] += a0 * b3v;
            acc[1][0] += a1 * b0v; acc[1][1] += a1 * b1v; acc[1][2] += a1 * b2v; acc[1][3] += a1 * b3v;
            acc[2][0] += a2 * b0v; acc[2][1] += a2 * b1v; acc[2][2] += a2 * b2v; acc[2][3] += a2 * b3v;
            acc[3][0] += a3 * b0v; acc[3][1] += a3 * b1v; acc[3][2] += a3 * b2v; acc[3][3] += a3 * b3v;
        }
    }
    __syncthreads();   // all As/Bs reads done; smem reusable as tile

    if (bn >= 512) {   // ---- V: plain store ----
        #pragma unroll
        for (int i = 0; i < 4; ++i) {
            int row = bm + tm + i;
            if (row < NN) {
                #pragma unroll
                for (int j = 0; j < 4; ++j)
                    Vbuf[(size_t)row * 256 + (bn - 512) + tn + j] = acc[i][j] + bf[bn + tn + j];
            }
        }
        return;
    }

    // ---- Q/K: performer features on the 64x64 head tile ----
    float scale = DNRM * rsqrtf(params[P_TAU]);
    #pragma unroll
    for (int i = 0; i < 4; ++i)
        #pragma unroll
        for (int j = 0; j < 4; ++j)
            tile[tm + i][tn + j] = (acc[i][j] + bf[bn + tn + j]) * scale;
    __syncthreads();

    int r = tid >> 2, q = tid & 3;      // 4 lanes cooperate per row; same wave
    int n = bm + r;
    const float* trow = tile[r];
    float dp = 0.f;
    #pragma unroll
    for (int d = q * 16; d < q * 16 + 16; ++d) dp += trow[d] * trow[d];
    dp += __shfl_xor(dp, 1);
    dp += __shfl_xor(dp, 2);
    float diag = dp * 0.5f;

    float dm[8];
    int nm = 0;
    float lmax = -3.0e38f;
    for (int m = q; m < MF; m += 4) {
        float s = 0.f;
        #pragma unroll
        for (int d = 0; d < DH; ++d) s += trow[d] * projL[m * DH + d];
        dm[nm++] = s;
        lmax = fmaxf(lmax, s);
    }
    float mx = fmaxf(lmax, __shfl_xor(lmax, 1));
    mx = fmaxf(mx, __shfl_xor(mx, 2));

    if (bn < 256) {   // Q: row-local stab, write qp
        int h = blockIdx.y;
        if (n < NN) {
            float* o = qp + ((size_t)n * NH + h) * MF;
            nm = 0;
            for (int m = q; m < MF; m += 4) o[m] = RATIO * (expf(dm[nm++] - diag - mx) + 1e-6f);
        }
    } else {          // K: store dash/diag, global per-head max
        int h = blockIdx.y - 4;
        if (n < NN) {
            float* o = dashK + ((size_t)n * NH + h) * MF;
            nm = 0;
            for (int m = q; m < MF; m += 4) o[m] = dm[nm++];
            if (q == 0) {
                diagK[(size_t)n * NH + h] = diag;
                atomicMax(&smaxL, encf(mx));
            }
        }
        __syncthreads();
        if (tid == 0) atomicMax(&stab[h], smaxL);
    }
}

// ---------------- keys pass 2: kp in-place + kpsum ----------------
__global__ __launch_bounds__(256) void k_kp(float* __restrict__ kp, const float* __restrict__ diagK,
                                            const u32* __restrict__ stab, float* __restrict__ kpsum)
{
    __shared__ float part[NH * MF];
    __shared__ float stabf[4];
    int tid = threadIdx.x;
    if (tid < NH * MF) part[tid] = 0.f;
    if (tid >= 128 && tid < 132) stabf[tid - 128] = decf(stab[tid - 128]);
    __syncthreads();
    int base = blockIdx.x * 64 * MF;   // 64 rows/block, exact: 1875*64 = 120000
    for (int i = tid; i < 64 * MF; i += 256) {
        int row = blockIdx.x * 64 + i / MF;
        int m = i - (i / MF) * MF;
        int h = row & 3;
        float v = RATIO * (expf(kp[base + i] - diagK[row] - stabf[h]) + 1e-6f);
        kp[base + i] = v;
        atomicAdd(&part[h * MF + m], v);
    }
    __syncthreads();
    if (tid < NH * MF) atomicAdd(&kpsum[tid], part[tid]);
}

// ---------------- attn_norm[n,h] = qp[n,h,:] . kpsum[h,:] ----------------
__global__ __launch_bounds__(256) void k_an(const float* __restrict__ qp, const float* __restrict__ kpsum,
                                            float* __restrict__ an)
{
    __shared__ float kps[NH * MF];
    int tid = threadIdx.x;
    if (tid < NH * MF) kps[tid] = kpsum[tid];
    __syncthreads();
    int idx = blockIdx.x * 256 + tid;
    if (idx >= NN * NH) return;
    int h = idx & 3;
    const float* q = qp + (size_t)idx * MF;
    float s = 0.f;
    #pragma unroll
    for (int m = 0; m < MF; ++m) s += q[m] * kps[h * MF + m];
    an[idx] = s;
}

// ---------------- kvs[h,k,m,d] & ksum[h,k,m] reduction over nodes ----------------
#define KVS_CHUNK 120
__global__ __launch_bounds__(320) void k_kvs(const float* __restrict__ kp, const void* __restrict__ gum,
                                             const float* __restrict__ Vbuf, const int* __restrict__ flag,
                                             float* __restrict__ kvs, float* __restrict__ ksum)
{
    __shared__ float kpL[MF];
    __shared__ float egL[KG];
    __shared__ float vL[DH];
    int tid = threadIdx.x;
    int h = blockIdx.y;
    int f32 = *flag;
    int n0 = blockIdx.x * KVS_CHUNK;
    int ki = tid / MF, mi = tid - ki * MF;   // valid for tid<300
    float acc[DH] = {};
    float ksacc = 0.f;
    for (int it = 0; it < KVS_CHUNK; ++it) {
        int n = n0 + it;
        __syncthreads();
        if (tid < MF)            kpL[tid] = kp[(size_t)n * (NH * MF) + h * MF + tid];
        else if (tid < MF + KG) {
            size_t gofs = (size_t)n * (NH * KG) + h * KG + (tid - MF);
            float g = f32 ? ((const float*)gum)[gofs] : u2f(((const u16*)gum)[gofs]);
            egL[tid - MF] = expf(g);
        }
        else if (tid < MF + KG + DH) vL[tid - MF - KG] = Vbuf[(size_t)n * 256 + h * 64 + (tid - MF - KG)];
        __syncthreads();
        if (tid < KG * MF) {
            float w = kpL[mi] * egL[ki];
            ksacc += w;
            #pragma unroll
            for (int d = 0; d < DH; ++d) acc[d] += w * vL[d];
        }
    }
    if (tid < KG * MF) {
        int base = ((h * KG + ki) * MF + mi) * DH;
        #pragma unroll
        for (int d = 0; d < DH; ++d) atomicAdd(&kvs[base + d], acc[d]);
        atomicAdd(&ksum[(h * KG + ki) * MF + mi], ksacc);
    }
}

// ---------------- per-edge attention weights -> link loss partials ----------------
__global__ __launch_bounds__(256) void k_edge(const int* __restrict__ ei, const float* __restrict__ qp,
                                              const float* __restrict__ kp, const float* __restrict__ an,
                                              const int* __restrict__ din, float* __restrict__ lossp)
{
    __shared__ float ls[256];
    int tid = threadIdx.x;
    int e = blockIdx.x * 256 + tid;
    float term = 0.f;
    if (e < NE) {
        int s = ei[e], t = ei[NE + e];
        float rd = 1.0f / (float)din[t];
        #pragma unroll
        for (int h = 0; h < NH; ++h) {
            const float* qv = qp + (size_t)(t * NH + h) * MF;
            const float* kv = kp + (size_t)(s * NH + h) * MF;
            float num = 0.f;
            #pragma unroll
            for (int m = 0; m < MF; ++m) num += qv[m] * kv[m];
            float A = num / an[t * NH + h];
            term += logf(A) * rd;
        }
    }
    ls[tid] = term;
    __syncthreads();
    for (int o = 128; o > 0; o >>= 1) {
        if (tid < o) ls[tid] += ls[tid + o];
        __syncthreads();
    }
    if (tid == 0) atomicAdd(&lossp[blockIdx.x & 1023], ls[0]);
}

// ---------------- final: attention readout + conv gather + Wo projection ----------------
__global__ __launch_bounds__(256) void k_final(
    const float* __restrict__ qp, const float* __restrict__ kvs, const float* __restrict__ ksum,
    const float* __restrict__ Vbuf, const int* __restrict__ csr, const int* __restrict__ offn,
    const int* __restrict__ din, const int* __restrict__ doutd,
    const float* __restrict__ params, float* __restrict__ out)
{
    __shared__ float qpL[NH * MF];
    __shared__ float rden[NH * KG];
    __shared__ float sL[256];
    __shared__ float sigb[4];
    int n = blockIdx.x, tid = threadIdx.x;
    if (tid < NH * MF) qpL[tid] = qp[(size_t)n * (NH * MF) + tid];
    if (tid >= 128 && tid < 132) {
        float bv = params[P_BBF + tid - 128];
        sigb[tid - 128] = 1.f / (1.f + expf(-bv));
    }
    __syncthreads();
    if (tid < NH * KG) {
        int h = tid / KG, k = tid - h * KG;
        float s = 0.f;
        #pragma unroll
        for (int m = 0; m < MF; ++m) s += qpL[h * MF + m] * ksum[(h * KG + k) * MF + m];
        rden[tid] = 1.0f / s;
    }
    __syncthreads();
    int h = tid >> 6, d = tid & 63;
    float acc = 0.f;
    for (int k = 0; k < KG; ++k) {
        const float* kv = kvs + (size_t)((h * KG + k) * MF) * DH + d;
        float s = 0.f;
        #pragma unroll
        for (int m = 0; m < MF; ++m) s += qpL[h * MF + m] * kv[m * DH];
        acc += s * rden[h * KG + k];
    }
    acc *= (1.0f / KG);
    int dn = din[n];
    if (dn > 0) {
        int o0 = offn[n];
        float rdin = 1.0f / (float)dn;
        float cacc = 0.f;
        for (int i = 0; i < dn; ++i) {
            int s = csr[o0 + i];
            float w = sqrtf(rdin / (float)doutd[s]);
            cacc += w * Vbuf[(size_t)s * 256 + h * 64 + d];
        }
        acc += sigb[h] * cacc;
    }
    sL[tid] = acc;
    __syncthreads();
    if (tid < 64) {
        float o = params[P_WOBF + tid];
        const float4* wr = (const float4*)(params + P_WOF + (size_t)tid * 256);
        #pragma unroll 8
        for (int c4 = 0; c4 < 64; ++c4) {
            float4 u = wr[c4];
            const float* sp = sL + c4 * 4;
            o += u.x * sp[0] + u.y * sp[1] + u.z * sp[2] + u.w * sp[3];
        }
        out[(size_t)n * 64 + tid] = o;   // fp32 output, per reference dtype
    }
}

// ---------------- loss finalize ----------------
__global__ __launch_bounds__(256) void k_loss(const float* __restrict__ lossp, float* __restrict__ out) {
    __shared__ float s[256];
    int tid = threadIdx.x;
    float v = 0.f;
    for (int i = tid; i < 1024; i += 256) v += lossp[i];
    s[tid] = v;
    __syncthreads();
    for (int o = 128; o > 0; o >>= 1) {
        if (tid < o) s[tid] += s[tid + o];
        __syncthreads();
    }
    if (tid == 0) out[(size_t)NN * 64] = s[0] / (float)(NE * NH);   // fp32 output
}

extern "C" void kernel_launch(void* const* d_in, const int* in_sizes, int n_in,
                              void* d_out, int out_size, void* d_ws, size_t ws_size,
                              hipStream_t stream)
{
    const void* z    = d_in[0];
    const int*  ei   = (const int*)d_in[1];
    const void* taup = d_in[2];
    const void* gum  = d_in[3];
    const void* proj = d_in[4];
    const void* Wq   = d_in[5];
    const void* bq   = d_in[6];
    const void* Wk   = d_in[7];
    const void* bk   = d_in[8];
    const void* Wv   = d_in[9];
    const void* bv   = d_in[10];
    const void* Wo   = d_in[11];
    const void* Wob  = d_in[12];
    const void* bb   = d_in[13];
    float* out = (float*)d_out;

    // ---- workspace carve-up (fp32 units), total ~64 MB ----
    float* Vbuf   = (float*)d_ws;                  //  7,680,000 : [N,256] V
    float* qpb    = Vbuf + (size_t)NN * 256;       //  3,600,000 : [N,H,M]
    float* kpb    = qpb + (size_t)NN * NH * MF;    //  3,600,000 : dashK then kp in-place
    float* diagK  = kpb + (size_t)NN * NH * MF;    //    120,000
    float* anb    = diagK + (size_t)NN * NH;       //    120,000
    int*   csr    = (int*)(anb + (size_t)NN * NH); //    480,000
    int*   offn   = csr + NE;                      //     30,000
    float* params = (float*)(offn + NN);           //    215,749 (+pad to 215,752)
    // ---- zeroed accumulator region ----
    float* kvs    = params + 215752;               //     76,800 : [H,K,M,D]
    float* ksum   = kvs + NH * KG * MF * DH;       //      1,200 : [H,K,M]
    float* kpsum  = ksum + NH * KG * MF;           //        120 : [H,M]
    int*   din    = (int*)(kpsum + NH * MF);       //     30,000
    int*   doutd  = din + NN;                      //     30,000
    int*   fill   = doutd + NN;                    //     30,000
    int*   counter = fill + NN;                    //          4
    u32*   stab   = (u32*)(counter + 4);           //          4
    float* lossp  = (float*)(stab + 4);            //      1,024
    int*   flag   = (int*)(lossp + 1024);          //          1
    size_t zero_bytes = (size_t)((char*)(flag + 1) - (char*)kvs);

    hipMemsetAsync(kvs, 0, zero_bytes, stream);

    k_detect<<<dim3(1), dim3(64), 0, stream>>>((const u16*)z, flag);
    k_cvt_params<<<dim3((P_TOTAL + 255) / 256), dim3(256), 0, stream>>>(
        Wq, Wk, Wv, bq, bk, bv, Wo, Wob, bb, proj, taup, params, flag);

    k_deg <<<dim3((NE + 255) / 256), dim3(256), 0, stream>>>(ei, din, doutd);
    k_off <<<dim3((NN + 255) / 256), dim3(256), 0, stream>>>(din, offn, counter);
    k_fill<<<dim3((NE + 255) / 256), dim3(256), 0, stream>>>(ei, offn, fill, csr);
    k_gemm_feat<<<dim3((NN + 63) / 64, 12), dim3(256), 0, stream>>>(
        z, params, flag, Vbuf, qpb, kpb, diagK, stab);
    k_kp  <<<dim3(NN * NH / 64), dim3(256), 0, stream>>>(kpb, diagK, stab, kpsum);
    k_an  <<<dim3((NN * NH + 255) / 256), dim3(256), 0, stream>>>(qpb, kpsum, anb);
    k_kvs <<<dim3(NN / KVS_CHUNK, NH), dim3(320), 0, stream>>>(kpb, gum, Vbuf, flag, kvs, ksum);
    k_edge<<<dim3((NE + 255) / 256), dim3(256), 0, stream>>>(ei, qpb, kpb, anb, din, lossp);
    k_final<<<dim3(NN), dim3(256), 0, stream>>>(qpb, kvs, ksum, Vbuf, csr, offn, din, doutd, params, out);
    k_loss<<<dim3(1), dim3(256), 0, stream>>>(lossp, out);
}

// Round 6
// 1630.714 us; speedup vs baseline: 1.6777x; 1.6777x over previous
//
#include <hip/hip_runtime.h>
#include <hip/hip_bf16.h>

#define NN 30000
#define NE 480000
#define NH 4
#define DH 64
#define MF 30
#define KG 10
#define RATIO 0.18257418583505536f   /* 1/sqrt(30) */
#define DNRM  0.35355339059327373f   /* 64^-0.25  */

// fp32 params block layout (element offsets)
#define P_WF    0        /* [768][256] Wq|Wk|Wv rows */
#define P_BF    196608   /* [768] bq|bk|bv */
#define P_WOF   197376   /* [64][256] Wo */
#define P_WOBF  213760   /* [64] Wo bias */
#define P_BBF   213824   /* [4] rb bias b */
#define P_PROJ  213828   /* [30][64] proj */
#define P_TAU   215748   /* scalar */
#define P_TOTAL 215749

typedef unsigned short u16;
typedef unsigned int   u32;

__device__ __forceinline__ float u2f(u16 u) { return __uint_as_float(((u32)u) << 16); }
// order-preserving float->uint encoding for atomicMax over signed floats
__device__ __forceinline__ u32  encf(float f) { u32 u = __float_as_uint(f); return (u & 0x80000000u) ? ~u : (u | 0x80000000u); }
__device__ __forceinline__ float decf(u32 u)  { return (u & 0x80000000u) ? __uint_as_float(u & 0x7FFFFFFFu) : __uint_as_float(~u); }

// ---------------- dtype detection (fp32 vs bf16 input tensors) ----------------
// Round-3/5 result: flag=1 on this harness (inputs fp32). Kept as a cheap guard.
__global__ void k_detect(const u16* __restrict__ z, int* __restrict__ flag) {
    if (threadIdx.x == 0 && blockIdx.x == 0) {
        int bad = 0;
        for (int i = 0; i < 256; i += 2) {
            u16 u = z[i];
            int e = (u >> 7) & 0xFF;
            if (u != 0 && !(e >= 100 && e <= 140)) bad++;
        }
        *flag = (bad > 16) ? 1 : 0;   // 1 = inputs are fp32
    }
}

// ---------------- stage all small params to fp32 ----------------
__global__ __launch_bounds__(256) void k_cvt_params(
    const void* Wq, const void* Wk, const void* Wv,
    const void* bq, const void* bk, const void* bv,
    const void* Wo, const void* Wob, const void* bb, const void* proj,
    const void* taup, float* __restrict__ params, const int* __restrict__ flag)
{
    int i = blockIdx.x * 256 + threadIdx.x;
    if (i >= P_TOTAL) return;
    int f = *flag;
    if (i == P_TAU) {
        float v = f ? ((const float*)taup)[0] : u2f(((const u16*)taup)[0]);
        if (!(v > 1e-6f && v < 1e6f)) {  // mixed-dtype defense for the 0-d scalar
            float ff = ((const float*)taup)[0];
            v = (ff > 1e-6f && ff < 1e6f) ? ff : 0.25f;
        }
        params[i] = v;
        return;
    }
    const void* src; int j;
    if      (i < 65536)  { src = Wq;  j = i; }
    else if (i < 131072) { src = Wk;  j = i - 65536; }
    else if (i < 196608) { src = Wv;  j = i - 131072; }
    else if (i < 196864) { src = bq;  j = i - 196608; }
    else if (i < 197120) { src = bk;  j = i - 196864; }
    else if (i < 197376) { src = bv;  j = i - 197120; }
    else if (i < 213760) { src = Wo;  j = i - 197376; }
    else if (i < 213824) { src = Wob; j = i - 213760; }
    else if (i < 213828) { src = bb;  j = i - 213824; }
    else                 { src = proj; j = i - P_PROJ; }
    params[i] = f ? ((const float*)src)[j] : u2f(((const u16*)src)[j]);
}

// ---------------- degrees ----------------
__global__ __launch_bounds__(256) void k_deg(const int* __restrict__ ei, int* __restrict__ din, int* __restrict__ dout) {
    int e = blockIdx.x * 256 + threadIdx.x;
    if (e >= NE) return;
    atomicAdd(&dout[ei[e]], 1);
    atomicAdd(&din[ei[NE + e]], 1);
}

// ---------------- scan-free CSR offsets ----------------
__global__ __launch_bounds__(256) void k_off(const int* __restrict__ din, int* __restrict__ offn, int* __restrict__ counter) {
    __shared__ int s[256];
    __shared__ int base;
    int tid = threadIdx.x;
    int n = blockIdx.x * 256 + tid;
    int v = (n < NN) ? din[n] : 0;
    s[tid] = v;
    __syncthreads();
    for (int o = 1; o < 256; o <<= 1) {
        int t = (tid >= o) ? s[tid - o] : 0;
        __syncthreads();
        s[tid] += t;
        __syncthreads();
    }
    if (tid == 255) base = atomicAdd(counter, s[255]);
    __syncthreads();
    if (n < NN) offn[n] = base + s[tid] - v;
}

__global__ __launch_bounds__(256) void k_fill(const int* __restrict__ ei, const int* __restrict__ offn,
                                              int* __restrict__ fill, int* __restrict__ csr) {
    int e = blockIdx.x * 256 + threadIdx.x;
    if (e >= NE) return;
    int s = ei[e], t = ei[NE + e];
    int pos = offn[t] + atomicAdd(&fill[t], 1);
    csr[pos] = s;
}

// ---------------- fused QKV GEMM + Performer feature epilogue ----------------
// grid (ceil(NN/64), 12): y 0..3 -> Q head y; y 4..7 -> K head y-4; y 8..11 -> V cols
__global__ __launch_bounds__(256) void k_gemm_feat(
    const void* __restrict__ zv, const float* __restrict__ params, const int* __restrict__ flag,
    float* __restrict__ Vbuf, float* __restrict__ qp,
    float* __restrict__ dashK, float* __restrict__ diagK, u32* __restrict__ stab)
{
    __shared__ float smem[4160 + 1920];   // As(32x65)|Bs(32x65) -> reused as tile(64x65); + projL
    __shared__ u32 smaxL;
    float (*As)[65]   = (float(*)[65])smem;
    float (*Bs)[65]   = (float(*)[65])(smem + 2080);
    float (*tile)[65] = (float(*)[65])smem;
    float* projL      = smem + 4160;

    const float* Wf = params + P_WF;
    const float* bf = params + P_BF;
    const int f32 = *flag;
    const int tid = threadIdx.x;
    const int bm = blockIdx.x * 64;
    const int bn = blockIdx.y * 64;

    if (bn < 512) {   // Q or K block: stage proj
        for (int i = tid; i < MF * DH; i += 256) projL[i] = params[P_PROJ + i];
    }
    if (tid == 0) smaxL = 0u;

    const int lm = tid >> 2;          // 0..63
    const int lk = (tid & 3) * 8;     // 0,8,16,24
    const int tm = (tid >> 4) * 4;
    const int tn = (tid & 15) * 4;
    float acc[4][4] = {};

    for (int k0 = 0; k0 < 256; k0 += 32) {
        __syncthreads();
        int row = bm + lm;
        float e[8] = {0.f, 0.f, 0.f, 0.f, 0.f, 0.f, 0.f, 0.f};
        if (row < NN) {
            if (f32) {
                const float4* zp = (const float4*)((const float*)zv + (size_t)row * 256 + k0 + lk);
                float4 a = zp[0], c = zp[1];
                e[0] = a.x; e[1] = a.y; e[2] = a.z; e[3] = a.w;
                e[4] = c.x; e[5] = c.y; e[6] = c.z; e[7] = c.w;
            } else {
                uint4 av = *(const uint4*)((const u16*)zv + (size_t)row * 256 + k0 + lk);
                e[0] = __uint_as_float(av.x << 16); e[1] = __uint_as_float(av.x & 0xFFFF0000u);
                e[2] = __uint_as_float(av.y << 16); e[3] = __uint_as_float(av.y & 0xFFFF0000u);
                e[4] = __uint_as_float(av.z << 16); e[5] = __uint_as_float(av.z & 0xFFFF0000u);
                e[6] = __uint_as_float(av.w << 16); e[7] = __uint_as_float(av.w & 0xFFFF0000u);
            }
        }
        #pragma unroll
        for (int j = 0; j < 8; ++j) As[lk + j][lm] = e[j];
        const float4* wr = (const float4*)(Wf + (size_t)(bn + lm) * 256 + k0 + lk);
        float4 b0 = wr[0], b1 = wr[1];
        Bs[lk + 0][lm] = b0.x; Bs[lk + 1][lm] = b0.y; Bs[lk + 2][lm] = b0.z; Bs[lk + 3][lm] = b0.w;
        Bs[lk + 4][lm] = b1.x; Bs[lk + 5][lm] = b1.y; Bs[lk + 6][lm] = b1.z; Bs[lk + 7][lm] = b1.w;
        __syncthreads();
        #pragma unroll
        for (int kk = 0; kk < 32; ++kk) {
            float a0 = As[kk][tm + 0], a1 = As[kk][tm + 1], a2 = As[kk][tm + 2], a3 = As[kk][tm + 3];
            float b0v = Bs[kk][tn + 0], b1v = Bs[kk][tn + 1], b2v = Bs[kk][tn + 2], b3v = Bs[kk][tn + 3];
            acc[0][0] += a0 * b0v; acc[0][1] += a0 * b1v; acc[0][2] += a0 * b2v; acc[0][3] += a0 * b3v;
            acc[1][0] += a1 * b0v; acc[1][1] += a1 * b1v; acc[1][2] += a1 * b2v; acc[1][3] += a1 * b3v;
            acc[2][0] += a2 * b0v; acc[2][1] += a2 * b1v; acc[2][2] += a2 * b2v; acc[2][3] += a2 * b3v;
            acc[3][0] += a3 * b0v; acc[3][1] += a3 * b1v; acc[3][2] += a3 * b2v; acc[3][3] += a3 * b3v;
        }
    }
    __syncthreads();   // all As/Bs reads done; smem reusable as tile

    if (bn >= 512) {   // ---- V: plain store ----
        #pragma unroll
        for (int i = 0; i < 4; ++i) {
            int row = bm + tm + i;
            if (row < NN) {
                #pragma unroll
                for (int j = 0; j < 4; ++j)
                    Vbuf[(size_t)row * 256 + (bn - 512) + tn + j] = acc[i][j] + bf[bn + tn + j];
            }
        }
        return;
    }

    // ---- Q/K: performer features on the 64x64 head tile ----
    float scale = DNRM * rsqrtf(params[P_TAU]);
    #pragma unroll
    for (int i = 0; i < 4; ++i)
        #pragma unroll
        for (int j = 0; j < 4; ++j)
            tile[tm + i][tn + j] = (acc[i][j] + bf[bn + tn + j]) * scale;
    __syncthreads();

    int r = tid >> 2, q = tid & 3;      // 4 lanes cooperate per row; same wave
    int n = bm + r;
    const float* trow = tile[r];
    float dp = 0.f;
    #pragma unroll
    for (int d = q * 16; d < q * 16 + 16; ++d) dp += trow[d] * trow[d];
    dp += __shfl_xor(dp, 1);
    dp += __shfl_xor(dp, 2);
    float diag = dp * 0.5f;

    float dm[8];
    int nm = 0;
    float lmax = -3.0e38f;
    for (int m = q; m < MF; m += 4) {
        float s = 0.f;
        #pragma unroll
        for (int d = 0; d < DH; ++d) s += trow[d] * projL[m * DH + d];
        dm[nm++] = s;
        lmax = fmaxf(lmax, s);
    }
    float mx = fmaxf(lmax, __shfl_xor(lmax, 1));
    mx = fmaxf(mx, __shfl_xor(mx, 2));

    if (bn < 256) {   // Q: row-local stab, write qp
        int h = blockIdx.y;
        if (n < NN) {
            float* o = qp + ((size_t)n * NH + h) * MF;
            nm = 0;
            for (int m = q; m < MF; m += 4) o[m] = RATIO * (expf(dm[nm++] - diag - mx) + 1e-6f);
        }
    } else {          // K: store dash/diag, global per-head max
        int h = blockIdx.y - 4;
        if (n < NN) {
            float* o = dashK + ((size_t)n * NH + h) * MF;
            nm = 0;
            for (int m = q; m < MF; m += 4) o[m] = dm[nm++];
            if (q == 0) {
                diagK[(size_t)n * NH + h] = diag;
                atomicMax(&smaxL, encf(mx));
            }
        }
        __syncthreads();
        if (tid == 0) atomicMax(&stab[h], smaxL);
    }
}

// ---------------- keys pass 2: kp in-place + kpsum ----------------
__global__ __launch_bounds__(256) void k_kp(float* __restrict__ kp, const float* __restrict__ diagK,
                                            const u32* __restrict__ stab, float* __restrict__ kpsum)
{
    __shared__ float part[NH * MF];
    __shared__ float stabf[4];
    int tid = threadIdx.x;
    if (tid < NH * MF) part[tid] = 0.f;
    if (tid >= 128 && tid < 132) stabf[tid - 128] = decf(stab[tid - 128]);
    __syncthreads();
    int base = blockIdx.x * 64 * MF;   // 64 rows/block, exact: 1875*64 = 120000
    for (int i = tid; i < 64 * MF; i += 256) {
        int row = blockIdx.x * 64 + i / MF;
        int m = i - (i / MF) * MF;
        int h = row & 3;
        float v = RATIO * (expf(kp[base + i] - diagK[row] - stabf[h]) + 1e-6f);
        kp[base + i] = v;
        atomicAdd(&part[h * MF + m], v);
    }
    __syncthreads();
    if (tid < NH * MF) atomicAdd(&kpsum[tid], part[tid]);
}

// ---------------- attn_norm[n,h] = qp[n,h,:] . kpsum[h,:] ----------------
__global__ __launch_bounds__(256) void k_an(const float* __restrict__ qp, const float* __restrict__ kpsum,
                                            float* __restrict__ an)
{
    __shared__ float kps[NH * MF];
    int tid = threadIdx.x;
    if (tid < NH * MF) kps[tid] = kpsum[tid];
    __syncthreads();
    int idx = blockIdx.x * 256 + tid;
    if (idx >= NN * NH) return;
    int h = idx & 3;
    const float* q = qp + (size_t)idx * MF;
    float s = 0.f;
    #pragma unroll
    for (int m = 0; m < MF; ++m) s += q[m] * kps[h * MF + m];
    an[idx] = s;
}

// ---------------- kvs[h,k,m,d] & ksum[h,k,m] reduction over nodes ----------------
// Restructured (round 6): grid (25 chunks, NH, 4 d-slices), 320 threads.
// Thread owns (k,m) with acc[16] IN REGISTERS (round-5 version spilled acc[64]
// to scratch: VGPR_Count=48 < 64 accumulators -> 2.8% VALUBusy, 1325 us).
// 40-node LDS tiles amortize barriers; atomics cut 19.5M -> ~1.9M.
#define KVS_CHUNKS 25
#define KVS_NPB (NN / KVS_CHUNKS)    /* 1200 nodes per block */
#define KVS_TS 40                    /* nodes per LDS tile */
#define KVS_DZ 16                    /* d-slice width, grid.z = DH/KVS_DZ = 4 */
__global__ __launch_bounds__(320) void k_kvs(const float* __restrict__ kp, const void* __restrict__ gum,
                                             const float* __restrict__ Vbuf, const int* __restrict__ flag,
                                             float* __restrict__ kvs, float* __restrict__ ksum)
{
    __shared__ float kpL[KVS_TS][MF];
    __shared__ float egL[KVS_TS][KG];
    __shared__ float vL[KVS_TS][KVS_DZ];
    int tid = threadIdx.x;
    int h = blockIdx.y;
    int z = blockIdx.z;
    int d0 = z * KVS_DZ;
    int f32 = *flag;
    int n0 = blockIdx.x * KVS_NPB;
    int ki = tid / MF, mi = tid - ki * MF;   // valid for tid<300
    float acc[KVS_DZ] = {};
    float ksacc = 0.f;
    for (int t0 = 0; t0 < KVS_NPB; t0 += KVS_TS) {
        __syncthreads();
        for (int i = tid; i < KVS_TS * MF; i += 320) {          // kp tile (coalesced)
            int j = i / MF, m = i - j * MF;
            kpL[j][m] = kp[(size_t)(n0 + t0 + j) * (NH * MF) + h * MF + m];
        }
        for (int i = tid; i < KVS_TS * KG; i += 320) {          // exp(gumbel) tile
            int j = i / KG, k = i - j * KG;
            size_t gofs = (size_t)(n0 + t0 + j) * (NH * KG) + h * KG + k;
            float g = f32 ? ((const float*)gum)[gofs] : u2f(((const u16*)gum)[gofs]);
            egL[j][k] = expf(g);
        }
        for (int i = tid; i < KVS_TS * KVS_DZ; i += 320) {      // V d-slice tile
            int j = i / KVS_DZ, dd = i - j * KVS_DZ;
            vL[j][dd] = Vbuf[(size_t)(n0 + t0 + j) * 256 + h * 64 + d0 + dd];
        }
        __syncthreads();
        if (tid < KG * MF) {
            for (int j = 0; j < KVS_TS; ++j) {
                float w = kpL[j][mi] * egL[j][ki];   // LDS broadcast-friendly
                ksacc += w;
                #pragma unroll
                for (int dd = 0; dd < KVS_DZ; ++dd) acc[dd] += w * vL[j][dd];
            }
        }
    }
    if (tid < KG * MF) {
        int base = ((h * KG + ki) * MF + mi) * DH + d0;
        #pragma unroll
        for (int dd = 0; dd < KVS_DZ; ++dd) atomicAdd(&kvs[base + dd], acc[dd]);
        if (z == 0) atomicAdd(&ksum[(h * KG + ki) * MF + mi], ksacc);
    }
}

// ---------------- per-edge attention weights -> link loss partials ----------------
__global__ __launch_bounds__(256) void k_edge(const int* __restrict__ ei, const float* __restrict__ qp,
                                              const float* __restrict__ kp, const float* __restrict__ an,
                                              const int* __restrict__ din, float* __restrict__ lossp)
{
    __shared__ float ls[256];
    int tid = threadIdx.x;
    int e = blockIdx.x * 256 + tid;
    float term = 0.f;
    if (e < NE) {
        int s = ei[e], t = ei[NE + e];
        float rd = 1.0f / (float)din[t];
        #pragma unroll
        for (int h = 0; h < NH; ++h) {
            const float* qv = qp + (size_t)(t * NH + h) * MF;
            const float* kv = kp + (size_t)(s * NH + h) * MF;
            float num = 0.f;
            #pragma unroll
            for (int m = 0; m < MF; ++m) num += qv[m] * kv[m];
            float A = num / an[t * NH + h];
            term += logf(A) * rd;
        }
    }
    ls[tid] = term;
    __syncthreads();
    for (int o = 128; o > 0; o >>= 1) {
        if (tid < o) ls[tid] += ls[tid + o];
        __syncthreads();
    }
    if (tid == 0) atomicAdd(&lossp[blockIdx.x & 1023], ls[0]);
}

// ---------------- final: attention readout + conv gather + Wo projection ----------------
__global__ __launch_bounds__(256) void k_final(
    const float* __restrict__ qp, const float* __restrict__ kvs, const float* __restrict__ ksum,
    const float* __restrict__ Vbuf, const int* __restrict__ csr, const int* __restrict__ offn,
    const int* __restrict__ din, const int* __restrict__ doutd,
    const float* __restrict__ params, float* __restrict__ out)
{
    __shared__ float qpL[NH * MF];
    __shared__ float rden[NH * KG];
    __shared__ float sL[256];
    __shared__ float sigb[4];
    int n = blockIdx.x, tid = threadIdx.x;
    if (tid < NH * MF) qpL[tid] = qp[(size_t)n * (NH * MF) + tid];
    if (tid >= 128 && tid < 132) {
        float bv = params[P_BBF + tid - 128];
        sigb[tid - 128] = 1.f / (1.f + expf(-bv));
    }
    __syncthreads();
    if (tid < NH * KG) {
        int h = tid / KG, k = tid - h * KG;
        float s = 0.f;
        #pragma unroll
        for (int m = 0; m < MF; ++m) s += qpL[h * MF + m] * ksum[(h * KG + k) * MF + m];
        rden[tid] = 1.0f / s;
    }
    __syncthreads();
    int h = tid >> 6, d = tid & 63;
    float acc = 0.f;
    for (int k = 0; k < KG; ++k) {
        const float* kv = kvs + (size_t)((h * KG + k) * MF) * DH + d;
        float s = 0.f;
        #pragma unroll
        for (int m = 0; m < MF; ++m) s += qpL[h * MF + m] * kv[m * DH];
        acc += s * rden[h * KG + k];
    }
    acc *= (1.0f / KG);
    int dn = din[n];
    if (dn > 0) {
        int o0 = offn[n];
        float rdin = 1.0f / (float)dn;
        float cacc = 0.f;
        for (int i = 0; i < dn; ++i) {
            int s = csr[o0 + i];
            float w = sqrtf(rdin / (float)doutd[s]);
            cacc += w * Vbuf[(size_t)s * 256 + h * 64 + d];
        }
        acc += sigb[h] * cacc;
    }
    sL[tid] = acc;
    __syncthreads();
    if (tid < 64) {
        float o = params[P_WOBF + tid];
        const float4* wr = (const float4*)(params + P_WOF + (size_t)tid * 256);
        #pragma unroll 8
        for (int c4 = 0; c4 < 64; ++c4) {
            float4 u = wr[c4];
            const float* sp = sL + c4 * 4;
            o += u.x * sp[0] + u.y * sp[1] + u.z * sp[2] + u.w * sp[3];
        }
        out[(size_t)n * 64 + tid] = o;   // fp32 output, per reference dtype
    }
}

// ---------------- loss finalize ----------------
__global__ __launch_bounds__(256) void k_loss(const float* __restrict__ lossp, float* __restrict__ out) {
    __shared__ float s[256];
    int tid = threadIdx.x;
    float v = 0.f;
    for (int i = tid; i < 1024; i += 256) v += lossp[i];
    s[tid] = v;
    __syncthreads();
    for (int o = 128; o > 0; o >>= 1) {
        if (tid < o) s[tid] += s[tid + o];
        __syncthreads();
    }
    if (tid == 0) out[(size_t)NN * 64] = s[0] / (float)(NE * NH);   // fp32 output
}

extern "C" void kernel_launch(void* const* d_in, const int* in_sizes, int n_in,
                              void* d_out, int out_size, void* d_ws, size_t ws_size,
                              hipStream_t stream)
{
    const void* z    = d_in[0];
    const int*  ei   = (const int*)d_in[1];
    const void* taup = d_in[2];
    const void* gum  = d_in[3];
    const void* proj = d_in[4];
    const void* Wq   = d_in[5];
    const void* bq   = d_in[6];
    const void* Wk   = d_in[7];
    const void* bk   = d_in[8];
    const void* Wv   = d_in[9];
    const void* bv   = d_in[10];
    const void* Wo   = d_in[11];
    const void* Wob  = d_in[12];
    const void* bb   = d_in[13];
    float* out = (float*)d_out;

    // ---- workspace carve-up (fp32 units), total ~64 MB ----
    float* Vbuf   = (float*)d_ws;                  //  7,680,000 : [N,256] V
    float* qpb    = Vbuf + (size_t)NN * 256;       //  3,600,000 : [N,H,M]
    float* kpb    = qpb + (size_t)NN * NH * MF;    //  3,600,000 : dashK then kp in-place
    float* diagK  = kpb + (size_t)NN * NH * MF;    //    120,000
    float* anb    = diagK + (size_t)NN * NH;       //    120,000
    int*   csr    = (int*)(anb + (size_t)NN * NH); //    480,000
    int*   offn   = csr + NE;                      //     30,000
    float* params = (float*)(offn + NN);           //    215,749 (+pad to 215,752)
    // ---- zeroed accumulator region ----
    float* kvs    = params + 215752;               //     76,800 : [H,K,M,D]
    float* ksum   = kvs + NH * KG * MF * DH;       //      1,200 : [H,K,M]
    float* kpsum  = ksum + NH * KG * MF;           //        120 : [H,M]
    int*   din    = (int*)(kpsum + NH * MF);       //     30,000
    int*   doutd  = din + NN;                      //     30,000
    int*   fill   = doutd + NN;                    //     30,000
    int*   counter = fill + NN;                    //          4
    u32*   stab   = (u32*)(counter + 4);           //          4
    float* lossp  = (float*)(stab + 4);            //      1,024
    int*   flag   = (int*)(lossp + 1024);          //          1
    size_t zero_bytes = (size_t)((char*)(flag + 1) - (char*)kvs);

    hipMemsetAsync(kvs, 0, zero_bytes, stream);

    k_detect<<<dim3(1), dim3(64), 0, stream>>>((const u16*)z, flag);
    k_cvt_params<<<dim3((P_TOTAL + 255) / 256), dim3(256), 0, stream>>>(
        Wq, Wk, Wv, bq, bk, bv, Wo, Wob, bb, proj, taup, params, flag);

    k_deg <<<dim3((NE + 255) / 256), dim3(256), 0, stream>>>(ei, din, doutd);
    k_off <<<dim3((NN + 255) / 256), dim3(256), 0, stream>>>(din, offn, counter);
    k_fill<<<dim3((NE + 255) / 256), dim3(256), 0, stream>>>(ei, offn, fill, csr);
    k_gemm_feat<<<dim3((NN + 63) / 64, 12), dim3(256), 0, stream>>>(
        z, params, flag, Vbuf, qpb, kpb, diagK, stab);
    k_kp  <<<dim3(NN * NH / 64), dim3(256), 0, stream>>>(kpb, diagK, stab, kpsum);
    k_an  <<<dim3((NN * NH + 255) / 256), dim3(256), 0, stream>>>(qpb, kpsum, anb);
    k_kvs <<<dim3(KVS_CHUNKS, NH, DH / KVS_DZ), dim3(320), 0, stream>>>(kpb, gum, Vbuf, flag, kvs, ksum);
    k_edge<<<dim3((NE + 255) / 256), dim3(256), 0, stream>>>(ei, qpb, kpb, anb, din, lossp);
    k_final<<<dim3(NN), dim3(256), 0, stream>>>(qpb, kvs, ksum, Vbuf, csr, offn, din, doutd, params, out);
    k_loss<<<dim3(1), dim3(256), 0, stream>>>(lossp, out);
}

// Round 7
// 1463.510 us; speedup vs baseline: 1.8694x; 1.1142x over previous
//
#include <hip/hip_runtime.h>
#include <hip/hip_bf16.h>

#define NN 30000
#define NE 480000
#define NH 4
#define DH 64
#define MF 30
#define KG 10
#define RATIO 0.18257418583505536f   /* 1/sqrt(30) */
#define DNRM  0.35355339059327373f   /* 64^-0.25  */

// fp32 params block layout (element offsets)
#define P_WF    0        /* [768][256] Wq|Wk|Wv rows */
#define P_BF    196608   /* [768] bq|bk|bv */
#define P_WOF   197376   /* [64][256] Wo */
#define P_WOBF  213760   /* [64] Wo bias */
#define P_BBF   213824   /* [4] rb bias b */
#define P_PROJ  213828   /* [30][64] proj */
#define P_TAU   215748   /* scalar */
#define P_TOTAL 215749

typedef unsigned short u16;
typedef unsigned int   u32;

__device__ __forceinline__ float u2f(u16 u) { return __uint_as_float(((u32)u) << 16); }
__device__ __forceinline__ u16  f2bf(float f) {  // round-to-nearest-even bf16
    u32 x = __float_as_uint(f);
    return (u16)((x + 0x7FFFu + ((x >> 16) & 1u)) >> 16);
}
// order-preserving float->uint encoding for atomicMax over signed floats
__device__ __forceinline__ u32  encf(float f) { u32 u = __float_as_uint(f); return (u & 0x80000000u) ? ~u : (u | 0x80000000u); }
__device__ __forceinline__ float decf(u32 u)  { return (u & 0x80000000u) ? __uint_as_float(u & 0x7FFFFFFFu) : __uint_as_float(~u); }

// ---------------- dtype detection (fp32 vs bf16 input tensors) ----------------
// Round-3/5 result: flag=1 on this harness (inputs fp32). Kept as a cheap guard.
__global__ void k_detect(const u16* __restrict__ z, int* __restrict__ flag) {
    if (threadIdx.x == 0 && blockIdx.x == 0) {
        int bad = 0;
        for (int i = 0; i < 256; i += 2) {
            u16 u = z[i];
            int e = (u >> 7) & 0xFF;
            if (u != 0 && !(e >= 100 && e <= 140)) bad++;
        }
        *flag = (bad > 16) ? 1 : 0;   // 1 = inputs are fp32
    }
}

// ---------------- stage all small params to fp32 ----------------
__global__ __launch_bounds__(256) void k_cvt_params(
    const void* Wq, const void* Wk, const void* Wv,
    const void* bq, const void* bk, const void* bv,
    const void* Wo, const void* Wob, const void* bb, const void* proj,
    const void* taup, float* __restrict__ params, const int* __restrict__ flag)
{
    int i = blockIdx.x * 256 + threadIdx.x;
    if (i >= P_TOTAL) return;
    int f = *flag;
    if (i == P_TAU) {
        float v = f ? ((const float*)taup)[0] : u2f(((const u16*)taup)[0]);
        if (!(v > 1e-6f && v < 1e6f)) {  // mixed-dtype defense for the 0-d scalar
            float ff = ((const float*)taup)[0];
            v = (ff > 1e-6f && ff < 1e6f) ? ff : 0.25f;
        }
        params[i] = v;
        return;
    }
    const void* src; int j;
    if      (i < 65536)  { src = Wq;  j = i; }
    else if (i < 131072) { src = Wk;  j = i - 65536; }
    else if (i < 196608) { src = Wv;  j = i - 131072; }
    else if (i < 196864) { src = bq;  j = i - 196608; }
    else if (i < 197120) { src = bk;  j = i - 196864; }
    else if (i < 197376) { src = bv;  j = i - 197120; }
    else if (i < 213760) { src = Wo;  j = i - 197376; }
    else if (i < 213824) { src = Wob; j = i - 213760; }
    else if (i < 213828) { src = bb;  j = i - 213824; }
    else                 { src = proj; j = i - P_PROJ; }
    params[i] = f ? ((const float*)src)[j] : u2f(((const u16*)src)[j]);
}

// ---------------- degrees ----------------
__global__ __launch_bounds__(256) void k_deg(const int* __restrict__ ei, int* __restrict__ din, int* __restrict__ dout) {
    int e = blockIdx.x * 256 + threadIdx.x;
    if (e >= NE) return;
    atomicAdd(&dout[ei[e]], 1);
    atomicAdd(&din[ei[NE + e]], 1);
}

// ---------------- scan-free CSR offsets ----------------
__global__ __launch_bounds__(256) void k_off(const int* __restrict__ din, int* __restrict__ offn, int* __restrict__ counter) {
    __shared__ int s[256];
    __shared__ int base;
    int tid = threadIdx.x;
    int n = blockIdx.x * 256 + tid;
    int v = (n < NN) ? din[n] : 0;
    s[tid] = v;
    __syncthreads();
    for (int o = 1; o < 256; o <<= 1) {
        int t = (tid >= o) ? s[tid - o] : 0;
        __syncthreads();
        s[tid] += t;
        __syncthreads();
    }
    if (tid == 255) base = atomicAdd(counter, s[255]);
    __syncthreads();
    if (n < NN) offn[n] = base + s[tid] - v;
}

// fill CSR + precompute per-edge conv weight w = rsqrt(din[t]*dout[s])
__global__ __launch_bounds__(256) void k_fill(const int* __restrict__ ei, const int* __restrict__ offn,
                                              int* __restrict__ fill, int* __restrict__ csr,
                                              const int* __restrict__ din, const int* __restrict__ dout,
                                              float* __restrict__ wedge) {
    int e = blockIdx.x * 256 + threadIdx.x;
    if (e >= NE) return;
    int s = ei[e], t = ei[NE + e];
    int pos = offn[t] + atomicAdd(&fill[t], 1);
    csr[pos] = s;
    wedge[pos] = rsqrtf((float)din[t] * (float)dout[s]);
}

// ---------------- fused QKV GEMM + Performer feature epilogue ----------------
// grid (ceil(NN/64), 12): y 0..3 -> Q head y; y 4..7 -> K head y-4; y 8..11 -> V cols
__global__ __launch_bounds__(256) void k_gemm_feat(
    const void* __restrict__ zv, const float* __restrict__ params, const int* __restrict__ flag,
    float* __restrict__ Vbuf, float* __restrict__ qp,
    float* __restrict__ dashK, float* __restrict__ diagK, u32* __restrict__ stab)
{
    __shared__ float smem[4160 + 1920];   // As(32x65)|Bs(32x65) -> reused as tile(64x65); + projL
    __shared__ u32 smaxL;
    float (*As)[65]   = (float(*)[65])smem;
    float (*Bs)[65]   = (float(*)[65])(smem + 2080);
    float (*tile)[65] = (float(*)[65])smem;
    float* projL      = smem + 4160;

    const float* Wf = params + P_WF;
    const float* bf = params + P_BF;
    const int f32 = *flag;
    const int tid = threadIdx.x;
    const int bm = blockIdx.x * 64;
    const int bn = blockIdx.y * 64;

    if (bn < 512) {   // Q or K block: stage proj
        for (int i = tid; i < MF * DH; i += 256) projL[i] = params[P_PROJ + i];
    }
    if (tid == 0) smaxL = 0u;

    const int lm = tid >> 2;          // 0..63
    const int lk = (tid & 3) * 8;     // 0,8,16,24
    const int tm = (tid >> 4) * 4;
    const int tn = (tid & 15) * 4;
    float acc[4][4] = {};

    for (int k0 = 0; k0 < 256; k0 += 32) {
        __syncthreads();
        int row = bm + lm;
        float e[8] = {0.f, 0.f, 0.f, 0.f, 0.f, 0.f, 0.f, 0.f};
        if (row < NN) {
            if (f32) {
                const float4* zp = (const float4*)((const float*)zv + (size_t)row * 256 + k0 + lk);
                float4 a = zp[0], c = zp[1];
                e[0] = a.x; e[1] = a.y; e[2] = a.z; e[3] = a.w;
                e[4] = c.x; e[5] = c.y; e[6] = c.z; e[7] = c.w;
            } else {
                uint4 av = *(const uint4*)((const u16*)zv + (size_t)row * 256 + k0 + lk);
                e[0] = __uint_as_float(av.x << 16); e[1] = __uint_as_float(av.x & 0xFFFF0000u);
                e[2] = __uint_as_float(av.y << 16); e[3] = __uint_as_float(av.y & 0xFFFF0000u);
                e[4] = __uint_as_float(av.z << 16); e[5] = __uint_as_float(av.z & 0xFFFF0000u);
                e[6] = __uint_as_float(av.w << 16); e[7] = __uint_as_float(av.w & 0xFFFF0000u);
            }
        }
        #pragma unroll
        for (int j = 0; j < 8; ++j) As[lk + j][lm] = e[j];
        const float4* wr = (const float4*)(Wf + (size_t)(bn + lm) * 256 + k0 + lk);
        float4 b0 = wr[0], b1 = wr[1];
        Bs[lk + 0][lm] = b0.x; Bs[lk + 1][lm] = b0.y; Bs[lk + 2][lm] = b0.z; Bs[lk + 3][lm] = b0.w;
        Bs[lk + 4][lm] = b1.x; Bs[lk + 5][lm] = b1.y; Bs[lk + 6][lm] = b1.z; Bs[lk + 7][lm] = b1.w;
        __syncthreads();
        #pragma unroll
        for (int kk = 0; kk < 32; ++kk) {
            float a0 = As[kk][tm + 0], a1 = As[kk][tm + 1], a2 = As[kk][tm + 2], a3 = As[kk][tm + 3];
            float b0v = Bs[kk][tn + 0], b1v = Bs[kk][tn + 1], b2v = Bs[kk][tn + 2], b3v = Bs[kk][tn + 3];
            acc[0][0] += a0 * b0v; acc[0][1] += a0 * b1v; acc[0][2] += a0 * b2v; acc[0][3] += a0 * b3v;
            acc[1][0] += a1 * b0v; acc[1][1] += a1 * b1v; acc[1][2] += a1 * b2v; acc[1][3] += a1 * b3v;
            acc[2][0] += a2 * b0v; acc[2][1] += a2 * b1v; acc[2][2] += a2 * b2v; acc[2][3] += a2 * b3v;
            acc[3][0] += a3 * b0v; acc[3][1] += a3 * b1v; acc[3][2] += a3 * b2v; acc[3][3] += a3 * b3v;
        }
    }
    __syncthreads();   // all As/Bs reads done; smem reusable as tile

    if (bn >= 512) {   // ---- V: plain store ----
        #pragma unroll
        for (int i = 0; i < 4; ++i) {
            int row = bm + tm + i;
            if (row < NN) {
                #pragma unroll
                for (int j = 0; j < 4; ++j)
                    Vbuf[(size_t)row * 256 + (bn - 512) + tn + j] = acc[i][j] + bf[bn + tn + j];
            }
        }
        return;
    }

    // ---- Q/K: performer features on the 64x64 head tile ----
    float scale = DNRM * rsqrtf(params[P_TAU]);
    #pragma unroll
    for (int i = 0; i < 4; ++i)
        #pragma unroll
        for (int j = 0; j < 4; ++j)
            tile[tm + i][tn + j] = (acc[i][j] + bf[bn + tn + j]) * scale;
    __syncthreads();

    int r = tid >> 2, q = tid & 3;      // 4 lanes cooperate per row; same wave
    int n = bm + r;
    const float* trow = tile[r];
    float dp = 0.f;
    #pragma unroll
    for (int d = q * 16; d < q * 16 + 16; ++d) dp += trow[d] * trow[d];
    dp += __shfl_xor(dp, 1);
    dp += __shfl_xor(dp, 2);
    float diag = dp * 0.5f;

    float dm[8];
    int nm = 0;
    float lmax = -3.0e38f;
    for (int m = q; m < MF; m += 4) {
        float s = 0.f;
        #pragma unroll
        for (int d = 0; d < DH; ++d) s += trow[d] * projL[m * DH + d];
        dm[nm++] = s;
        lmax = fmaxf(lmax, s);
    }
    float mx = fmaxf(lmax, __shfl_xor(lmax, 1));
    mx = fmaxf(mx, __shfl_xor(mx, 2));

    if (bn < 256) {   // Q: row-local stab, write qp
        int h = blockIdx.y;
        if (n < NN) {
            float* o = qp + ((size_t)n * NH + h) * MF;
            nm = 0;
            for (int m = q; m < MF; m += 4) o[m] = RATIO * (expf(dm[nm++] - diag - mx) + 1e-6f);
        }
    } else {          // K: store dash/diag, global per-head max
        int h = blockIdx.y - 4;
        if (n < NN) {
            float* o = dashK + ((size_t)n * NH + h) * MF;
            nm = 0;
            for (int m = q; m < MF; m += 4) o[m] = dm[nm++];
            if (q == 0) {
                diagK[(size_t)n * NH + h] = diag;
                atomicMax(&smaxL, encf(mx));
            }
        }
        __syncthreads();
        if (tid == 0) atomicMax(&stab[h], smaxL);
    }
}

// ---------------- keys pass 2: kp in-place + kpsum ----------------
__global__ __launch_bounds__(256) void k_kp(float* __restrict__ kp, const float* __restrict__ diagK,
                                            const u32* __restrict__ stab, float* __restrict__ kpsum)
{
    __shared__ float part[NH * MF];
    __shared__ float stabf[4];
    int tid = threadIdx.x;
    if (tid < NH * MF) part[tid] = 0.f;
    if (tid >= 128 && tid < 132) stabf[tid - 128] = decf(stab[tid - 128]);
    __syncthreads();
    int base = blockIdx.x * 64 * MF;   // 64 rows/block, exact: 1875*64 = 120000
    for (int i = tid; i < 64 * MF; i += 256) {
        int row = blockIdx.x * 64 + i / MF;
        int m = i - (i / MF) * MF;
        int h = row & 3;
        float v = RATIO * (expf(kp[base + i] - diagK[row] - stabf[h]) + 1e-6f);
        kp[base + i] = v;
        atomicAdd(&part[h * MF + m], v);
    }
    __syncthreads();
    if (tid < NH * MF) atomicAdd(&kpsum[tid], part[tid]);
}

// ---------------- attn_norm[n,h] = qp[n,h,:] . kpsum[h,:] ----------------
__global__ __launch_bounds__(256) void k_an(const float* __restrict__ qp, const float* __restrict__ kpsum,
                                            float* __restrict__ an)
{
    __shared__ float kps[NH * MF];
    int tid = threadIdx.x;
    if (tid < NH * MF) kps[tid] = kpsum[tid];
    __syncthreads();
    int idx = blockIdx.x * 256 + tid;
    if (idx >= NN * NH) return;
    int h = idx & 3;
    const float* q = qp + (size_t)idx * MF;
    float s = 0.f;
    #pragma unroll
    for (int m = 0; m < MF; ++m) s += q[m] * kps[h * MF + m];
    an[idx] = s;
}

// ---------------- kvs[h,k,m,d] & ksum[h,k,m] reduction over nodes ----------------
#define KVS_CHUNKS 25
#define KVS_NPB (NN / KVS_CHUNKS)    /* 1200 nodes per block */
#define KVS_TS 40                    /* nodes per LDS tile */
#define KVS_DZ 16                    /* d-slice width, grid.z = DH/KVS_DZ = 4 */
__global__ __launch_bounds__(320) void k_kvs(const float* __restrict__ kp, const void* __restrict__ gum,
                                             const float* __restrict__ Vbuf, const int* __restrict__ flag,
                                             float* __restrict__ kvs, float* __restrict__ ksum)
{
    __shared__ float kpL[KVS_TS][MF];
    __shared__ float egL[KVS_TS][KG];
    __shared__ float vL[KVS_TS][KVS_DZ];
    int tid = threadIdx.x;
    int h = blockIdx.y;
    int z = blockIdx.z;
    int d0 = z * KVS_DZ;
    int f32 = *flag;
    int n0 = blockIdx.x * KVS_NPB;
    int ki = tid / MF, mi = tid - ki * MF;   // valid for tid<300
    float acc[KVS_DZ] = {};
    float ksacc = 0.f;
    for (int t0 = 0; t0 < KVS_NPB; t0 += KVS_TS) {
        __syncthreads();
        for (int i = tid; i < KVS_TS * MF; i += 320) {          // kp tile (coalesced)
            int j = i / MF, m = i - j * MF;
            kpL[j][m] = kp[(size_t)(n0 + t0 + j) * (NH * MF) + h * MF + m];
        }
        for (int i = tid; i < KVS_TS * KG; i += 320) {          // exp(gumbel) tile
            int j = i / KG, k = i - j * KG;
            size_t gofs = (size_t)(n0 + t0 + j) * (NH * KG) + h * KG + k;
            float g = f32 ? ((const float*)gum)[gofs] : u2f(((const u16*)gum)[gofs]);
            egL[j][k] = expf(g);
        }
        for (int i = tid; i < KVS_TS * KVS_DZ; i += 320) {      // V d-slice tile
            int j = i / KVS_DZ, dd = i - j * KVS_DZ;
            vL[j][dd] = Vbuf[(size_t)(n0 + t0 + j) * 256 + h * 64 + d0 + dd];
        }
        __syncthreads();
        if (tid < KG * MF) {
            for (int j = 0; j < KVS_TS; ++j) {
                float w = kpL[j][mi] * egL[j][ki];   // LDS broadcast-friendly
                ksacc += w;
                #pragma unroll
                for (int dd = 0; dd < KVS_DZ; ++dd) acc[dd] += w * vL[j][dd];
            }
        }
    }
    if (tid < KG * MF) {
        int base = ((h * KG + ki) * MF + mi) * DH + d0;
        #pragma unroll
        for (int dd = 0; dd < KVS_DZ; ++dd) atomicAdd(&kvs[base + dd], acc[dd]);
        if (z == 0) atomicAdd(&ksum[(h * KG + ki) * MF + mi], ksacc);
    }
}

// ---------------- per-edge attention weights -> link loss partials ----------------
__global__ __launch_bounds__(256) void k_edge(const int* __restrict__ ei, const float* __restrict__ qp,
                                              const float* __restrict__ kp, const float* __restrict__ an,
                                              const int* __restrict__ din, float* __restrict__ lossp)
{
    __shared__ float ls[256];
    int tid = threadIdx.x;
    int e = blockIdx.x * 256 + tid;
    float term = 0.f;
    if (e < NE) {
        int s = ei[e], t = ei[NE + e];
        float rd = 1.0f / (float)din[t];
        #pragma unroll
        for (int h = 0; h < NH; ++h) {
            const float* qv = qp + (size_t)(t * NH + h) * MF;
            const float* kv = kp + (size_t)(s * NH + h) * MF;
            float num = 0.f;
            #pragma unroll
            for (int m = 0; m < MF; ++m) num += qv[m] * kv[m];
            float A = num / an[t * NH + h];
            term += logf(A) * rd;
        }
    }
    ls[tid] = term;
    __syncthreads();
    for (int o = 128; o > 0; o >>= 1) {
        if (tid < o) ls[tid] += ls[tid + o];
        __syncthreads();
    }
    if (tid == 0) atomicAdd(&lossp[blockIdx.x & 1023], ls[0]);
}

// ---------------- attention readout: 16 nodes/block, kvs staged in LDS ----------------
// Replaces the kvs-re-read storm of the old k_final: 30000x300KB (9 GB L2)
// -> 1875x(10x30KB) = 560 MB. Register blocking 4 nodes x 4 d per thread.
// Thread map: h = tid>>6 (wave = head), jg = (tid>>4)&3, dg = tid&15.
// Output: mean_k(num/den) as bf16 into zatt[N][256] (reuses dead kpb region).
#define AT_NT 16
__global__ __launch_bounds__(256) void k_attn(
    const float* __restrict__ qp, const float* __restrict__ kvs, const float* __restrict__ ksum,
    u16* __restrict__ zatt)
{
    __shared__ float qpTf[NH * 484];          // plane h: [m][j] stride 16, plane pad->484
    __shared__ float kvL[NH * 1924];          // plane h: [m][d] stride 64, plane pad->1924
    __shared__ float rdenL[AT_NT * NH * KG];  // [j][h][k]
    __shared__ float ksL[NH * KG * MF];
    int tid = threadIdx.x;
    int n0 = blockIdx.x * AT_NT;

    for (int i = tid; i < AT_NT * NH * MF; i += 256) {   // qp -> transposed LDS
        int j = i / (NH * MF); int r = i - j * (NH * MF);
        int h = r / MF; int m = r - h * MF;
        qpTf[h * 484 + m * 16 + j] = qp[(size_t)(n0 + j) * (NH * MF) + r];
    }
    for (int i = tid; i < NH * KG * MF; i += 256) ksL[i] = ksum[i];
    __syncthreads();
    for (int i = tid; i < AT_NT * NH * KG; i += 256) {   // rden[j][h][k] = 1/(qp.ksum)
        int j = i / (NH * KG); int r = i - j * (NH * KG);
        int h = r / KG; int k = r - h * KG;
        float s = 0.f;
        #pragma unroll
        for (int m = 0; m < MF; ++m) s += qpTf[h * 484 + m * 16 + j] * ksL[(h * KG + k) * MF + m];
        rdenL[i] = 1.0f / s;
    }

    const int h  = tid >> 6;
    const int jg = (tid >> 4) & 3;
    const int dg = tid & 15;
    float acc[4][4] = {};
    for (int k = 0; k < KG; ++k) {
        __syncthreads();
        for (int i = tid; i < NH * MF * DH; i += 256) {  // stage kvs[:,k,:,:]
            int hh = i / (MF * DH); int r = i - hh * (MF * DH);
            kvL[hh * 1924 + r] = kvs[((size_t)(hh * KG + k) * MF) * DH + r];
        }
        __syncthreads();
        float ps[4][4] = {};
        const float* qb = qpTf + h * 484 + jg * 4;
        const float* kb = kvL + h * 1924 + dg * 4;
        #pragma unroll
        for (int m = 0; m < MF; ++m) {
            float4 a = *(const float4*)(qb + m * 16);
            float4 b = *(const float4*)(kb + m * 64);
            ps[0][0] += a.x * b.x; ps[0][1] += a.x * b.y; ps[0][2] += a.x * b.z; ps[0][3] += a.x * b.w;
            ps[1][0] += a.y * b.x; ps[1][1] += a.y * b.y; ps[1][2] += a.y * b.z; ps[1][3] += a.y * b.w;
            ps[2][0] += a.z * b.x; ps[2][1] += a.z * b.y; ps[2][2] += a.z * b.z; ps[2][3] += a.z * b.w;
            ps[3][0] += a.w * b.x; ps[3][1] += a.w * b.y; ps[3][2] += a.w * b.z; ps[3][3] += a.w * b.w;
        }
        #pragma unroll
        for (int j4 = 0; j4 < 4; ++j4) {
            float rd = rdenL[(jg * 4 + j4) * (NH * KG) + h * KG + k];
            #pragma unroll
            for (int d4 = 0; d4 < 4; ++d4) acc[j4][d4] += ps[j4][d4] * rd;
        }
    }
    #pragma unroll
    for (int j4 = 0; j4 < 4; ++j4) {
        int n = n0 + jg * 4 + j4;
        #pragma unroll
        for (int d4 = 0; d4 < 4; ++d4)
            zatt[(size_t)n * 256 + h * 64 + dg * 4 + d4] = f2bf(acc[j4][d4] * (1.0f / KG));
    }
}

// ---------------- conv gather (4-way ILP) + zatt add + Wo projection ----------------
__global__ __launch_bounds__(256) void k_conv(
    const u16* __restrict__ zatt, const float* __restrict__ Vbuf,
    const int* __restrict__ csr, const float* __restrict__ wedge,
    const int* __restrict__ offn, const int* __restrict__ din,
    const float* __restrict__ params, float* __restrict__ out)
{
    __shared__ float sL[256];
    __shared__ float sigb[4];
    int n = blockIdx.x, tid = threadIdx.x;
    if (tid < 4) sigb[tid] = 1.f / (1.f + expf(-params[P_BBF + tid]));
    int h = tid >> 6;
    int dn = din[n], o0 = offn[n];
    float cacc = 0.f;
    int i = 0;
    for (; i + 4 <= dn; i += 4) {
        int s0 = csr[o0 + i], s1 = csr[o0 + i + 1], s2 = csr[o0 + i + 2], s3 = csr[o0 + i + 3];
        float w0 = wedge[o0 + i], w1 = wedge[o0 + i + 1], w2 = wedge[o0 + i + 2], w3 = wedge[o0 + i + 3];
        float v0 = Vbuf[(size_t)s0 * 256 + tid];
        float v1 = Vbuf[(size_t)s1 * 256 + tid];
        float v2 = Vbuf[(size_t)s2 * 256 + tid];
        float v3 = Vbuf[(size_t)s3 * 256 + tid];
        cacc += w0 * v0 + w1 * v1 + w2 * v2 + w3 * v3;
    }
    for (; i < dn; ++i) cacc += wedge[o0 + i] * Vbuf[(size_t)csr[o0 + i] * 256 + tid];
    __syncthreads();
    sL[tid] = u2f(zatt[(size_t)n * 256 + tid]) + sigb[h] * cacc;
    __syncthreads();
    if (tid < 64) {
        float o = params[P_WOBF + tid];
        const float4* wr = (const float4*)(params + P_WOF + (size_t)tid * 256);
        #pragma unroll 8
        for (int c4 = 0; c4 < 64; ++c4) {
            float4 u = wr[c4];
            const float* sp = sL + c4 * 4;
            o += u.x * sp[0] + u.y * sp[1] + u.z * sp[2] + u.w * sp[3];
        }
        out[(size_t)n * 64 + tid] = o;   // fp32 output, per reference dtype
    }
}

// ---------------- loss finalize ----------------
__global__ __launch_bounds__(256) void k_loss(const float* __restrict__ lossp, float* __restrict__ out) {
    __shared__ float s[256];
    int tid = threadIdx.x;
    float v = 0.f;
    for (int i = tid; i < 1024; i += 256) v += lossp[i];
    s[tid] = v;
    __syncthreads();
    for (int o = 128; o > 0; o >>= 1) {
        if (tid < o) s[tid] += s[tid + o];
        __syncthreads();
    }
    if (tid == 0) out[(size_t)NN * 64] = s[0] / (float)(NE * NH);   // fp32 output
}

extern "C" void kernel_launch(void* const* d_in, const int* in_sizes, int n_in,
                              void* d_out, int out_size, void* d_ws, size_t ws_size,
                              hipStream_t stream)
{
    const void* z    = d_in[0];
    const int*  ei   = (const int*)d_in[1];
    const void* taup = d_in[2];
    const void* gum  = d_in[3];
    const void* proj = d_in[4];
    const void* Wq   = d_in[5];
    const void* bq   = d_in[6];
    const void* Wk   = d_in[7];
    const void* bk   = d_in[8];
    const void* Wv   = d_in[9];
    const void* bv   = d_in[10];
    const void* Wo   = d_in[11];
    const void* Wob  = d_in[12];
    const void* bb   = d_in[13];
    float* out = (float*)d_out;

    // ---- workspace carve-up (fp32 units), total ~66 MB ----
    float* Vbuf   = (float*)d_ws;                  //  7,680,000 : [N,256] V
    float* qpb    = Vbuf + (size_t)NN * 256;       //  3,600,000 : [N,H,M]
    float* kpb    = qpb + (size_t)NN * NH * MF;    //  3,600,000 : dashK then kp in-place
    float* diagK  = kpb + (size_t)NN * NH * MF;    //    120,000
    float* anb    = diagK + (size_t)NN * NH;       //    120,000
    // zatt (bf16 [N,256] = 7.68M u16 = 3.84M fp32 slots) reuses kpb+diagK+anb,
    // all dead after k_edge. k_attn runs after k_edge/k_kvs -> safe.
    u16*   zatt   = (u16*)kpb;
    int*   csr    = (int*)(anb + (size_t)NN * NH); //    480,000
    int*   offn   = csr + NE;                      //     30,000
    float* params = (float*)(offn + NN);           //    215,749 (+pad to 215,752)
    // ---- zeroed accumulator region ----
    float* kvs    = params + 215752;               //     76,800 : [H,K,M,D]
    float* ksum   = kvs + NH * KG * MF * DH;       //      1,200 : [H,K,M]
    float* kpsum  = ksum + NH * KG * MF;           //        120 : [H,M]
    int*   din    = (int*)(kpsum + NH * MF);       //     30,000
    int*   doutd  = din + NN;                      //     30,000
    int*   fill   = doutd + NN;                    //     30,000
    int*   counter = fill + NN;                    //          4
    u32*   stab   = (u32*)(counter + 4);           //          4
    float* lossp  = (float*)(stab + 4);            //      1,024
    int*   flag   = (int*)(lossp + 1024);          //          4
    float* wedge  = (float*)(flag + 4);            //    480,000 (not zeroed; fully written)
    size_t zero_bytes = (size_t)((char*)(flag + 4) - (char*)kvs);

    hipMemsetAsync(kvs, 0, zero_bytes, stream);

    k_detect<<<dim3(1), dim3(64), 0, stream>>>((const u16*)z, flag);
    k_cvt_params<<<dim3((P_TOTAL + 255) / 256), dim3(256), 0, stream>>>(
        Wq, Wk, Wv, bq, bk, bv, Wo, Wob, bb, proj, taup, params, flag);

    k_deg <<<dim3((NE + 255) / 256), dim3(256), 0, stream>>>(ei, din, doutd);
    k_off <<<dim3((NN + 255) / 256), dim3(256), 0, stream>>>(din, offn, counter);
    k_fill<<<dim3((NE + 255) / 256), dim3(256), 0, stream>>>(ei, offn, fill, csr, din, doutd, wedge);
    k_gemm_feat<<<dim3((NN + 63) / 64, 12), dim3(256), 0, stream>>>(
        z, params, flag, Vbuf, qpb, kpb, diagK, stab);
    k_kp  <<<dim3(NN * NH / 64), dim3(256), 0, stream>>>(kpb, diagK, stab, kpsum);
    k_an  <<<dim3((NN * NH + 255) / 256), dim3(256), 0, stream>>>(qpb, kpsum, anb);
    k_kvs <<<dim3(KVS_CHUNKS, NH, DH / KVS_DZ), dim3(320), 0, stream>>>(kpb, gum, Vbuf, flag, kvs, ksum);
    k_edge<<<dim3((NE + 255) / 256), dim3(256), 0, stream>>>(ei, qpb, kpb, anb, din, lossp);
    // zatt overwrites kpb/diagK/anb from here on (stream-ordered after their last readers)
    k_attn<<<dim3(NN / AT_NT), dim3(256), 0, stream>>>(qpb, kvs, ksum, zatt);
    k_conv<<<dim3(NN), dim3(256), 0, stream>>>(zatt, Vbuf, csr, wedge, offn, din, params, out);
    k_loss<<<dim3(1), dim3(256), 0, stream>>>(lossp, out);
}

// Round 8
// 1254.404 us; speedup vs baseline: 2.1810x; 1.1667x over previous
//
#include <hip/hip_runtime.h>
#include <hip/hip_bf16.h>

#define NN 30000
#define NE 480000
#define NH 4
#define DH 64
#define MF 30
#define KG 10
#define RATIO 0.18257418583505536f   /* 1/sqrt(30) */
#define DNRM  0.35355339059327373f   /* 64^-0.25  */

// fp32 params block layout (element offsets)
#define P_WF    0        /* [768][256] Wq|Wk|Wv rows */
#define P_BF    196608   /* [768] bq|bk|bv */
#define P_WOF   197376   /* [64][256] Wo */
#define P_WOBF  213760   /* [64] Wo bias */
#define P_BBF   213824   /* [4] rb bias b */
#define P_PROJ  213828   /* [30][64] proj */
#define P_TAU   215748   /* scalar */
#define P_TOTAL 215749

typedef unsigned short u16;
typedef unsigned int   u32;

__device__ __forceinline__ float u2f(u16 u) { return __uint_as_float(((u32)u) << 16); }
__device__ __forceinline__ u16  f2bf(float f) {  // round-to-nearest-even bf16
    u32 x = __float_as_uint(f);
    return (u16)((x + 0x7FFFu + ((x >> 16) & 1u)) >> 16);
}
// order-preserving float->uint encoding for atomicMax over signed floats
__device__ __forceinline__ u32  encf(float f) { u32 u = __float_as_uint(f); return (u & 0x80000000u) ? ~u : (u | 0x80000000u); }
__device__ __forceinline__ float decf(u32 u)  { return (u & 0x80000000u) ? __uint_as_float(u & 0x7FFFFFFFu) : __uint_as_float(~u); }

// ---------------- dtype detection (fp32 vs bf16 input tensors) ----------------
// Round-3/5 result: flag=1 on this harness (inputs fp32). Kept as a cheap guard.
__global__ void k_detect(const u16* __restrict__ z, int* __restrict__ flag) {
    if (threadIdx.x == 0 && blockIdx.x == 0) {
        int bad = 0;
        for (int i = 0; i < 256; i += 2) {
            u16 u = z[i];
            int e = (u >> 7) & 0xFF;
            if (u != 0 && !(e >= 100 && e <= 140)) bad++;
        }
        *flag = (bad > 16) ? 1 : 0;   // 1 = inputs are fp32
    }
}

// ---------------- stage all small params to fp32 ----------------
__global__ __launch_bounds__(256) void k_cvt_params(
    const void* Wq, const void* Wk, const void* Wv,
    const void* bq, const void* bk, const void* bv,
    const void* Wo, const void* Wob, const void* bb, const void* proj,
    const void* taup, float* __restrict__ params, const int* __restrict__ flag)
{
    int i = blockIdx.x * 256 + threadIdx.x;
    if (i >= P_TOTAL) return;
    int f = *flag;
    if (i == P_TAU) {
        float v = f ? ((const float*)taup)[0] : u2f(((const u16*)taup)[0]);
        if (!(v > 1e-6f && v < 1e6f)) {  // mixed-dtype defense for the 0-d scalar
            float ff = ((const float*)taup)[0];
            v = (ff > 1e-6f && ff < 1e6f) ? ff : 0.25f;
        }
        params[i] = v;
        return;
    }
    const void* src; int j;
    if      (i < 65536)  { src = Wq;  j = i; }
    else if (i < 131072) { src = Wk;  j = i - 65536; }
    else if (i < 196608) { src = Wv;  j = i - 131072; }
    else if (i < 196864) { src = bq;  j = i - 196608; }
    else if (i < 197120) { src = bk;  j = i - 196864; }
    else if (i < 197376) { src = bv;  j = i - 197120; }
    else if (i < 213760) { src = Wo;  j = i - 197376; }
    else if (i < 213824) { src = Wob; j = i - 213760; }
    else if (i < 213828) { src = bb;  j = i - 213824; }
    else                 { src = proj; j = i - P_PROJ; }
    params[i] = f ? ((const float*)src)[j] : u2f(((const u16*)src)[j]);
}

// ---------------- degrees ----------------
__global__ __launch_bounds__(256) void k_deg(const int* __restrict__ ei, int* __restrict__ din, int* __restrict__ dout) {
    int e = blockIdx.x * 256 + threadIdx.x;
    if (e >= NE) return;
    atomicAdd(&dout[ei[e]], 1);
    atomicAdd(&din[ei[NE + e]], 1);
}

// ---------------- scan-free CSR offsets ----------------
__global__ __launch_bounds__(256) void k_off(const int* __restrict__ din, int* __restrict__ offn, int* __restrict__ counter) {
    __shared__ int s[256];
    __shared__ int base;
    int tid = threadIdx.x;
    int n = blockIdx.x * 256 + tid;
    int v = (n < NN) ? din[n] : 0;
    s[tid] = v;
    __syncthreads();
    for (int o = 1; o < 256; o <<= 1) {
        int t = (tid >= o) ? s[tid - o] : 0;
        __syncthreads();
        s[tid] += t;
        __syncthreads();
    }
    if (tid == 255) base = atomicAdd(counter, s[255]);
    __syncthreads();
    if (n < NN) offn[n] = base + s[tid] - v;
}

// fill CSR + precompute per-edge conv weight w = rsqrt(din[t]*dout[s])
__global__ __launch_bounds__(256) void k_fill(const int* __restrict__ ei, const int* __restrict__ offn,
                                              int* __restrict__ fill, int* __restrict__ csr,
                                              const int* __restrict__ din, const int* __restrict__ dout,
                                              float* __restrict__ wedge) {
    int e = blockIdx.x * 256 + threadIdx.x;
    if (e >= NE) return;
    int s = ei[e], t = ei[NE + e];
    int pos = offn[t] + atomicAdd(&fill[t], 1);
    csr[pos] = s;
    wedge[pos] = rsqrtf((float)din[t] * (float)dout[s]);
}

// ---------------- fused QKV GEMM + Performer feature epilogue ----------------
// grid (ceil(NN/64), 12): y 0..3 -> Q head y; y 4..7 -> K head y-4; y 8..11 -> V cols
__global__ __launch_bounds__(256) void k_gemm_feat(
    const void* __restrict__ zv, const float* __restrict__ params, const int* __restrict__ flag,
    float* __restrict__ Vbuf, float* __restrict__ qp, u16* __restrict__ qp16,
    float* __restrict__ dashK, float* __restrict__ diagK, u32* __restrict__ stab)
{
    __shared__ float smem[4160 + 1920];   // As(32x65)|Bs(32x65) -> reused as tile(64x65); + projL
    __shared__ u32 smaxL;
    float (*As)[65]   = (float(*)[65])smem;
    float (*Bs)[65]   = (float(*)[65])(smem + 2080);
    float (*tile)[65] = (float(*)[65])smem;
    float* projL      = smem + 4160;

    const float* Wf = params + P_WF;
    const float* bf = params + P_BF;
    const int f32 = *flag;
    const int tid = threadIdx.x;
    const int bm = blockIdx.x * 64;
    const int bn = blockIdx.y * 64;

    if (bn < 512) {   // Q or K block: stage proj
        for (int i = tid; i < MF * DH; i += 256) projL[i] = params[P_PROJ + i];
    }
    if (tid == 0) smaxL = 0u;

    const int lm = tid >> 2;          // 0..63
    const int lk = (tid & 3) * 8;     // 0,8,16,24
    const int tm = (tid >> 4) * 4;
    const int tn = (tid & 15) * 4;
    float acc[4][4] = {};

    for (int k0 = 0; k0 < 256; k0 += 32) {
        __syncthreads();
        int row = bm + lm;
        float e[8] = {0.f, 0.f, 0.f, 0.f, 0.f, 0.f, 0.f, 0.f};
        if (row < NN) {
            if (f32) {
                const float4* zp = (const float4*)((const float*)zv + (size_t)row * 256 + k0 + lk);
                float4 a = zp[0], c = zp[1];
                e[0] = a.x; e[1] = a.y; e[2] = a.z; e[3] = a.w;
                e[4] = c.x; e[5] = c.y; e[6] = c.z; e[7] = c.w;
            } else {
                uint4 av = *(const uint4*)((const u16*)zv + (size_t)row * 256 + k0 + lk);
                e[0] = __uint_as_float(av.x << 16); e[1] = __uint_as_float(av.x & 0xFFFF0000u);
                e[2] = __uint_as_float(av.y << 16); e[3] = __uint_as_float(av.y & 0xFFFF0000u);
                e[4] = __uint_as_float(av.z << 16); e[5] = __uint_as_float(av.z & 0xFFFF0000u);
                e[6] = __uint_as_float(av.w << 16); e[7] = __uint_as_float(av.w & 0xFFFF0000u);
            }
        }
        #pragma unroll
        for (int j = 0; j < 8; ++j) As[lk + j][lm] = e[j];
        const float4* wr = (const float4*)(Wf + (size_t)(bn + lm) * 256 + k0 + lk);
        float4 b0 = wr[0], b1 = wr[1];
        Bs[lk + 0][lm] = b0.x; Bs[lk + 1][lm] = b0.y; Bs[lk + 2][lm] = b0.z; Bs[lk + 3][lm] = b0.w;
        Bs[lk + 4][lm] = b1.x; Bs[lk + 5][lm] = b1.y; Bs[lk + 6][lm] = b1.z; Bs[lk + 7][lm] = b1.w;
        __syncthreads();
        #pragma unroll
        for (int kk = 0; kk < 32; ++kk) {
            float a0 = As[kk][tm + 0], a1 = As[kk][tm + 1], a2 = As[kk][tm + 2], a3 = As[kk][tm + 3];
            float b0v = Bs[kk][tn + 0], b1v = Bs[kk][tn + 1], b2v = Bs[kk][tn + 2], b3v = Bs[kk][tn + 3];
            acc[0][0] += a0 * b0v; acc[0][1] += a0 * b1v; acc[0][2] += a0 * b2v; acc[0][3] += a0 * b3v;
            acc[1][0] += a1 * b0v; acc[1][1] += a1 * b1v; acc[1][2] += a1 * b2v; acc[1][3] += a1 * b3v;
            acc[2][0] += a2 * b0v; acc[2][1] += a2 * b1v; acc[2][2] += a2 * b2v; acc[2][3] += a2 * b3v;
            acc[3][0] += a3 * b0v; acc[3][1] += a3 * b1v; acc[3][2] += a3 * b2v; acc[3][3] += a3 * b3v;
        }
    }
    __syncthreads();   // all As/Bs reads done; smem reusable as tile

    if (bn >= 512) {   // ---- V: plain store ----
        #pragma unroll
        for (int i = 0; i < 4; ++i) {
            int row = bm + tm + i;
            if (row < NN) {
                #pragma unroll
                for (int j = 0; j < 4; ++j)
                    Vbuf[(size_t)row * 256 + (bn - 512) + tn + j] = acc[i][j] + bf[bn + tn + j];
            }
        }
        return;
    }

    // ---- Q/K: performer features on the 64x64 head tile ----
    float scale = DNRM * rsqrtf(params[P_TAU]);
    #pragma unroll
    for (int i = 0; i < 4; ++i)
        #pragma unroll
        for (int j = 0; j < 4; ++j)
            tile[tm + i][tn + j] = (acc[i][j] + bf[bn + tn + j]) * scale;
    __syncthreads();

    int r = tid >> 2, q = tid & 3;      // 4 lanes cooperate per row; same wave
    int n = bm + r;
    const float* trow = tile[r];
    float dp = 0.f;
    #pragma unroll
    for (int d = q * 16; d < q * 16 + 16; ++d) dp += trow[d] * trow[d];
    dp += __shfl_xor(dp, 1);
    dp += __shfl_xor(dp, 2);
    float diag = dp * 0.5f;

    float dm[8];
    int nm = 0;
    float lmax = -3.0e38f;
    for (int m = q; m < MF; m += 4) {
        float s = 0.f;
        #pragma unroll
        for (int d = 0; d < DH; ++d) s += trow[d] * projL[m * DH + d];
        dm[nm++] = s;
        lmax = fmaxf(lmax, s);
    }
    float mx = fmaxf(lmax, __shfl_xor(lmax, 1));
    mx = fmaxf(mx, __shfl_xor(mx, 2));

    if (bn < 256) {   // Q: row-local stab, write qp (fp32) + packed bf16 copy for k_edge
        int h = blockIdx.y;
        if (n < NN) {
            float* o = qp + ((size_t)n * NH + h) * MF;
            u16* o16 = qp16 + ((size_t)n * NH + h) * 32;
            nm = 0;
            for (int m = q; m < MF; m += 4) {
                float v = RATIO * (expf(dm[nm++] - diag - mx) + 1e-6f);
                o[m] = v;
                o16[m] = f2bf(v);
            }
            if (q == 0) { o16[30] = 0; o16[31] = 0; }   // zero pad for uint4 dot
        }
    } else {          // K: store dash/diag, global per-head max
        int h = blockIdx.y - 4;
        if (n < NN) {
            float* o = dashK + ((size_t)n * NH + h) * MF;
            nm = 0;
            for (int m = q; m < MF; m += 4) o[m] = dm[nm++];
            if (q == 0) {
                diagK[(size_t)n * NH + h] = diag;
                atomicMax(&smaxL, encf(mx));
            }
        }
        __syncthreads();
        if (tid == 0) atomicMax(&stab[h], smaxL);
    }
}

// ---------------- keys pass 2: kp in-place + kpsum + packed bf16 copy ----------------
__global__ __launch_bounds__(256) void k_kp(float* __restrict__ kp, const float* __restrict__ diagK,
                                            const u32* __restrict__ stab, float* __restrict__ kpsum,
                                            u16* __restrict__ kp16)
{
    __shared__ float part[NH * MF];
    __shared__ float stabf[4];
    int tid = threadIdx.x;
    if (tid < NH * MF) part[tid] = 0.f;
    if (tid >= 128 && tid < 132) stabf[tid - 128] = decf(stab[tid - 128]);
    __syncthreads();
    int base = blockIdx.x * 64 * MF;   // 64 rows/block, exact: 1875*64 = 120000
    for (int i = tid; i < 64 * MF; i += 256) {
        int row = blockIdx.x * 64 + i / MF;
        int m = i - (i / MF) * MF;
        int h = row & 3;
        float v = RATIO * (expf(kp[base + i] - diagK[row] - stabf[h]) + 1e-6f);
        kp[base + i] = v;
        kp16[(size_t)row * 32 + m] = f2bf(v);
        atomicAdd(&part[h * MF + m], v);
    }
    if (tid < 64) {   // zero pad entries for uint4 dot
        int row = blockIdx.x * 64 + tid;
        kp16[(size_t)row * 32 + 30] = 0;
        kp16[(size_t)row * 32 + 31] = 0;
    }
    __syncthreads();
    if (tid < NH * MF) atomicAdd(&kpsum[tid], part[tid]);
}

// ---------------- attn_norm[n,h] = qp[n,h,:] . kpsum[h,:] ----------------
__global__ __launch_bounds__(256) void k_an(const float* __restrict__ qp, const float* __restrict__ kpsum,
                                            float* __restrict__ an)
{
    __shared__ float kps[NH * MF];
    int tid = threadIdx.x;
    if (tid < NH * MF) kps[tid] = kpsum[tid];
    __syncthreads();
    int idx = blockIdx.x * 256 + tid;
    if (idx >= NN * NH) return;
    int h = idx & 3;
    const float* q = qp + (size_t)idx * MF;
    float s = 0.f;
    #pragma unroll
    for (int m = 0; m < MF; ++m) s += q[m] * kps[h * MF + m];
    an[idx] = s;
}

// ---------------- kvs[h,k,m,d] & ksum[h,k,m] reduction over nodes ----------------
#define KVS_CHUNKS 25
#define KVS_NPB (NN / KVS_CHUNKS)    /* 1200 nodes per block */
#define KVS_TS 40                    /* nodes per LDS tile */
#define KVS_DZ 16                    /* d-slice width, grid.z = DH/KVS_DZ = 4 */
__global__ __launch_bounds__(320) void k_kvs(const float* __restrict__ kp, const void* __restrict__ gum,
                                             const float* __restrict__ Vbuf, const int* __restrict__ flag,
                                             float* __restrict__ kvs, float* __restrict__ ksum)
{
    __shared__ float kpL[KVS_TS][MF];
    __shared__ float egL[KVS_TS][KG];
    __shared__ float vL[KVS_TS][KVS_DZ];
    int tid = threadIdx.x;
    int h = blockIdx.y;
    int z = blockIdx.z;
    int d0 = z * KVS_DZ;
    int f32 = *flag;
    int n0 = blockIdx.x * KVS_NPB;
    int ki = tid / MF, mi = tid - ki * MF;   // valid for tid<300
    float acc[KVS_DZ] = {};
    float ksacc = 0.f;
    for (int t0 = 0; t0 < KVS_NPB; t0 += KVS_TS) {
        __syncthreads();
        for (int i = tid; i < KVS_TS * MF; i += 320) {          // kp tile (coalesced)
            int j = i / MF, m = i - j * MF;
            kpL[j][m] = kp[(size_t)(n0 + t0 + j) * (NH * MF) + h * MF + m];
        }
        for (int i = tid; i < KVS_TS * KG; i += 320) {          // exp(gumbel) tile
            int j = i / KG, k = i - j * KG;
            size_t gofs = (size_t)(n0 + t0 + j) * (NH * KG) + h * KG + k;
            float g = f32 ? ((const float*)gum)[gofs] : u2f(((const u16*)gum)[gofs]);
            egL[j][k] = expf(g);
        }
        for (int i = tid; i < KVS_TS * KVS_DZ; i += 320) {      // V d-slice tile
            int j = i / KVS_DZ, dd = i - j * KVS_DZ;
            vL[j][dd] = Vbuf[(size_t)(n0 + t0 + j) * 256 + h * 64 + d0 + dd];
        }
        __syncthreads();
        if (tid < KG * MF) {
            for (int j = 0; j < KVS_TS; ++j) {
                float w = kpL[j][mi] * egL[j][ki];   // LDS broadcast-friendly
                ksacc += w;
                #pragma unroll
                for (int dd = 0; dd < KVS_DZ; ++dd) acc[dd] += w * vL[j][dd];
            }
        }
    }
    if (tid < KG * MF) {
        int base = ((h * KG + ki) * MF + mi) * DH + d0;
        #pragma unroll
        for (int dd = 0; dd < KVS_DZ; ++dd) atomicAdd(&kvs[base + dd], acc[dd]);
        if (z == 0) atomicAdd(&ksum[(h * KG + ki) * MF + mi], ksacc);
    }
}

// ---------------- per-edge attention weights -> link loss partials ----------------
// Round 8: 4 lanes per edge (lane = head), bf16-packed qp16/kp16 rows (64 B,
// uint4 loads). Replaces 1-thread-per-edge scalar gather (970 B/edge scalar,
// 41 ms under serialized profiling, 26% occ, VALUBusy 0.8%).
__global__ __launch_bounds__(256) void k_edge(const int* __restrict__ ei,
                                              const u16* __restrict__ qp16, const u16* __restrict__ kp16,
                                              const float* __restrict__ an,
                                              const int* __restrict__ din, float* __restrict__ lossp)
{
    __shared__ float ls[64];
    int tid = threadIdx.x;
    int eg = tid >> 2, h = tid & 3;
    int e = blockIdx.x * 64 + eg;           // grid = NE/64 exact
    int s = ei[e], t = ei[NE + e];
    const uint4* qv = (const uint4*)(qp16 + ((size_t)t * NH + h) * 32);
    const uint4* kv = (const uint4*)(kp16 + ((size_t)s * NH + h) * 32);
    float num = 0.f;
    #pragma unroll
    for (int c = 0; c < 4; ++c) {
        uint4 a = qv[c], b = kv[c];
        num += u2f((u16)(a.x & 0xFFFF)) * u2f((u16)(b.x & 0xFFFF))
             + u2f((u16)(a.x >> 16))    * u2f((u16)(b.x >> 16))
             + u2f((u16)(a.y & 0xFFFF)) * u2f((u16)(b.y & 0xFFFF))
             + u2f((u16)(a.y >> 16))    * u2f((u16)(b.y >> 16))
             + u2f((u16)(a.z & 0xFFFF)) * u2f((u16)(b.z & 0xFFFF))
             + u2f((u16)(a.z >> 16))    * u2f((u16)(b.z >> 16))
             + u2f((u16)(a.w & 0xFFFF)) * u2f((u16)(b.w & 0xFFFF))
             + u2f((u16)(a.w >> 16))    * u2f((u16)(b.w >> 16));
    }
    float term = logf(num / an[(size_t)t * NH + h]);
    term += __shfl_xor(term, 1);
    term += __shfl_xor(term, 2);
    if (h == 0) ls[eg] = term / (float)din[t];
    __syncthreads();
    if (tid < 64) {
        float v = ls[tid];
        #pragma unroll
        for (int o = 32; o > 0; o >>= 1) v += __shfl_xor(v, o);
        if (tid == 0) atomicAdd(&lossp[blockIdx.x & 1023], v);
    }
}

// ---------------- attention readout: 16 nodes/block, kvs staged in LDS ----------------
#define AT_NT 16
__global__ __launch_bounds__(256) void k_attn(
    const float* __restrict__ qp, const float* __restrict__ kvs, const float* __restrict__ ksum,
    u16* __restrict__ zatt)
{
    __shared__ float qpTf[NH * 484];          // plane h: [m][j] stride 16, plane pad->484
    __shared__ float kvL[NH * 1924];          // plane h: [m][d] stride 64, plane pad->1924
    __shared__ float rdenL[AT_NT * NH * KG];  // [j][h][k]
    __shared__ float ksL[NH * KG * MF];
    int tid = threadIdx.x;
    int n0 = blockIdx.x * AT_NT;

    for (int i = tid; i < AT_NT * NH * MF; i += 256) {   // qp -> transposed LDS
        int j = i / (NH * MF); int r = i - j * (NH * MF);
        int h = r / MF; int m = r - h * MF;
        qpTf[h * 484 + m * 16 + j] = qp[(size_t)(n0 + j) * (NH * MF) + r];
    }
    for (int i = tid; i < NH * KG * MF; i += 256) ksL[i] = ksum[i];
    __syncthreads();
    for (int i = tid; i < AT_NT * NH * KG; i += 256) {   // rden[j][h][k] = 1/(qp.ksum)
        int j = i / (NH * KG); int r = i - j * (NH * KG);
        int h = r / KG; int k = r - h * KG;
        float s = 0.f;
        #pragma unroll
        for (int m = 0; m < MF; ++m) s += qpTf[h * 484 + m * 16 + j] * ksL[(h * KG + k) * MF + m];
        rdenL[i] = 1.0f / s;
    }

    const int h  = tid >> 6;
    const int jg = (tid >> 4) & 3;
    const int dg = tid & 15;
    float acc[4][4] = {};
    for (int k = 0; k < KG; ++k) {
        __syncthreads();
        for (int i = tid; i < NH * MF * DH; i += 256) {  // stage kvs[:,k,:,:]
            int hh = i / (MF * DH); int r = i - hh * (MF * DH);
            kvL[hh * 1924 + r] = kvs[((size_t)(hh * KG + k) * MF) * DH + r];
        }
        __syncthreads();
        float ps[4][4] = {};
        const float* qb = qpTf + h * 484 + jg * 4;
        const float* kb = kvL + h * 1924 + dg * 4;
        #pragma unroll
        for (int m = 0; m < MF; ++m) {
            float4 a = *(const float4*)(qb + m * 16);
            float4 b = *(const float4*)(kb + m * 64);
            ps[0][0] += a.x * b.x; ps[0][1] += a.x * b.y; ps[0][2] += a.x * b.z; ps[0][3] += a.x * b.w;
            ps[1][0] += a.y * b.x; ps[1][1] += a.y * b.y; ps[1][2] += a.y * b.z; ps[1][3] += a.y * b.w;
            ps[2][0] += a.z * b.x; ps[2][1] += a.z * b.y; ps[2][2] += a.z * b.z; ps[2][3] += a.z * b.w;
            ps[3][0] += a.w * b.x; ps[3][1] += a.w * b.y; ps[3][2] += a.w * b.z; ps[3][3] += a.w * b.w;
        }
        #pragma unroll
        for (int j4 = 0; j4 < 4; ++j4) {
            float rd = rdenL[(jg * 4 + j4) * (NH * KG) + h * KG + k];
            #pragma unroll
            for (int d4 = 0; d4 < 4; ++d4) acc[j4][d4] += ps[j4][d4] * rd;
        }
    }
    #pragma unroll
    for (int j4 = 0; j4 < 4; ++j4) {
        int n = n0 + jg * 4 + j4;
        #pragma unroll
        for (int d4 = 0; d4 < 4; ++d4)
            zatt[(size_t)n * 256 + h * 64 + dg * 4 + d4] = f2bf(acc[j4][d4] * (1.0f / KG));
    }
}

// ---------------- conv gather (4-way ILP) + zatt add + Wo projection ----------------
__global__ __launch_bounds__(256) void k_conv(
    const u16* __restrict__ zatt, const float* __restrict__ Vbuf,
    const int* __restrict__ csr, const float* __restrict__ wedge,
    const int* __restrict__ offn, const int* __restrict__ din,
    const float* __restrict__ params, float* __restrict__ out)
{
    __shared__ float sL[256];
    __shared__ float sigb[4];
    int n = blockIdx.x, tid = threadIdx.x;
    if (tid < 4) sigb[tid] = 1.f / (1.f + expf(-params[P_BBF + tid]));
    int h = tid >> 6;
    int dn = din[n], o0 = offn[n];
    float cacc = 0.f;
    int i = 0;
    for (; i + 4 <= dn; i += 4) {
        int s0 = csr[o0 + i], s1 = csr[o0 + i + 1], s2 = csr[o0 + i + 2], s3 = csr[o0 + i + 3];
        float w0 = wedge[o0 + i], w1 = wedge[o0 + i + 1], w2 = wedge[o0 + i + 2], w3 = wedge[o0 + i + 3];
        float v0 = Vbuf[(size_t)s0 * 256 + tid];
        float v1 = Vbuf[(size_t)s1 * 256 + tid];
        float v2 = Vbuf[(size_t)s2 * 256 + tid];
        float v3 = Vbuf[(size_t)s3 * 256 + tid];
        cacc += w0 * v0 + w1 * v1 + w2 * v2 + w3 * v3;
    }
    for (; i < dn; ++i) cacc += wedge[o0 + i] * Vbuf[(size_t)csr[o0 + i] * 256 + tid];
    __syncthreads();
    sL[tid] = u2f(zatt[(size_t)n * 256 + tid]) + sigb[h] * cacc;
    __syncthreads();
    if (tid < 64) {
        float o = params[P_WOBF + tid];
        const float4* wr = (const float4*)(params + P_WOF + (size_t)tid * 256);
        #pragma unroll 8
        for (int c4 = 0; c4 < 64; ++c4) {
            float4 u = wr[c4];
            const float* sp = sL + c4 * 4;
            o += u.x * sp[0] + u.y * sp[1] + u.z * sp[2] + u.w * sp[3];
        }
        out[(size_t)n * 64 + tid] = o;   // fp32 output, per reference dtype
    }
}

// ---------------- loss finalize ----------------
__global__ __launch_bounds__(256) void k_loss(const float* __restrict__ lossp, float* __restrict__ out) {
    __shared__ float s[256];
    int tid = threadIdx.x;
    float v = 0.f;
    for (int i = tid; i < 1024; i += 256) v += lossp[i];
    s[tid] = v;
    __syncthreads();
    for (int o = 128; o > 0; o >>= 1) {
        if (tid < o) s[tid] += s[tid + o];
        __syncthreads();
    }
    if (tid == 0) out[(size_t)NN * 64] = s[0] / (float)(NE * NH);   // fp32 output
}

extern "C" void kernel_launch(void* const* d_in, const int* in_sizes, int n_in,
                              void* d_out, int out_size, void* d_ws, size_t ws_size,
                              hipStream_t stream)
{
    const void* z    = d_in[0];
    const int*  ei   = (const int*)d_in[1];
    const void* taup = d_in[2];
    const void* gum  = d_in[3];
    const void* proj = d_in[4];
    const void* Wq   = d_in[5];
    const void* bq   = d_in[6];
    const void* Wk   = d_in[7];
    const void* bk   = d_in[8];
    const void* Wv   = d_in[9];
    const void* bv   = d_in[10];
    const void* Wo   = d_in[11];
    const void* Wob  = d_in[12];
    const void* bb   = d_in[13];
    float* out = (float*)d_out;

    // ---- workspace carve-up (fp32 units), total ~82 MB ----
    float* Vbuf   = (float*)d_ws;                  //  7,680,000 : [N,256] V
    float* qpb    = Vbuf + (size_t)NN * 256;       //  3,600,000 : [N,H,M]
    float* kpb    = qpb + (size_t)NN * NH * MF;    //  3,600,000 : dashK then kp in-place
    float* diagK  = kpb + (size_t)NN * NH * MF;    //    120,000
    float* anb    = diagK + (size_t)NN * NH;       //    120,000
    // zatt (bf16 [N,256] = 7.68M u16 = 3.84M fp32 slots) reuses kpb+diagK+anb,
    // all dead after k_edge. k_attn runs after k_edge/k_kvs -> safe.
    u16*   zatt   = (u16*)kpb;
    int*   csr    = (int*)(anb + (size_t)NN * NH); //    480,000
    int*   offn   = csr + NE;                      //     30,000
    float* params = (float*)(offn + NN);           //    215,749 (+pad to 215,752)
    // ---- zeroed accumulator region ----
    float* kvs    = params + 215752;               //     76,800 : [H,K,M,D]
    float* ksum   = kvs + NH * KG * MF * DH;       //      1,200 : [H,K,M]
    float* kpsum  = ksum + NH * KG * MF;           //        120 : [H,M]
    int*   din    = (int*)(kpsum + NH * MF);       //     30,000
    int*   doutd  = din + NN;                      //     30,000
    int*   fill   = doutd + NN;                    //     30,000
    int*   counter = fill + NN;                    //          4
    u32*   stab   = (u32*)(counter + 4);           //          4
    float* lossp  = (float*)(stab + 4);            //      1,024
    int*   flag   = (int*)(lossp + 1024);          //          4
    float* wedge  = (float*)(flag + 4);            //    480,000 (not zeroed; fully written)
    u16*   qp16   = (u16*)(wedge + NE);            //  3,840,000 u16 : [N,H,32] bf16 qp
    u16*   kp16   = qp16 + (size_t)NN * NH * 32;   //  3,840,000 u16 : [N,H,32] bf16 kp
    size_t zero_bytes = (size_t)((char*)(flag + 4) - (char*)kvs);

    hipMemsetAsync(kvs, 0, zero_bytes, stream);

    k_detect<<<dim3(1), dim3(64), 0, stream>>>((const u16*)z, flag);
    k_cvt_params<<<dim3((P_TOTAL + 255) / 256), dim3(256), 0, stream>>>(
        Wq, Wk, Wv, bq, bk, bv, Wo, Wob, bb, proj, taup, params, flag);

    k_deg <<<dim3((NE + 255) / 256), dim3(256), 0, stream>>>(ei, din, doutd);
    k_off <<<dim3((NN + 255) / 256), dim3(256), 0, stream>>>(din, offn, counter);
    k_fill<<<dim3((NE + 255) / 256), dim3(256), 0, stream>>>(ei, offn, fill, csr, din, doutd, wedge);
    k_gemm_feat<<<dim3((NN + 63) / 64, 12), dim3(256), 0, stream>>>(
        z, params, flag, Vbuf, qpb, qp16, kpb, diagK, stab);
    k_kp  <<<dim3(NN * NH / 64), dim3(256), 0, stream>>>(kpb, diagK, stab, kpsum, kp16);
    k_an  <<<dim3((NN * NH + 255) / 256), dim3(256), 0, stream>>>(qpb, kpsum, anb);
    k_kvs <<<dim3(KVS_CHUNKS, NH, DH / KVS_DZ), dim3(320), 0, stream>>>(kpb, gum, Vbuf, flag, kvs, ksum);
    k_edge<<<dim3(NE / 64), dim3(256), 0, stream>>>(ei, qp16, kp16, anb, din, lossp);
    // zatt overwrites kpb/diagK/anb from here on (stream-ordered after their last readers)
    k_attn<<<dim3(NN / AT_NT), dim3(256), 0, stream>>>(qpb, kvs, ksum, zatt);
    k_conv<<<dim3(NN), dim3(256), 0, stream>>>(zatt, Vbuf, csr, wedge, offn, din, params, out);
    k_loss<<<dim3(1), dim3(256), 0, stream>>>(lossp, out);
}

// Round 9
// 1174.900 us; speedup vs baseline: 2.3286x; 1.0677x over previous
//
#include <hip/hip_runtime.h>
#include <hip/hip_bf16.h>

#define NN 30000
#define NE 480000
#define NH 4
#define DH 64
#define MF 30
#define KG 10
#define RATIO 0.18257418583505536f   /* 1/sqrt(30) */
#define DNRM  0.35355339059327373f   /* 64^-0.25  */

// fp32 params block layout (element offsets)
#define P_WF    0        /* [768][256] Wq|Wk|Wv rows */
#define P_BF    196608   /* [768] bq|bk|bv */
#define P_WOF   197376   /* [64][256] Wo */
#define P_WOBF  213760   /* [64] Wo bias */
#define P_BBF   213824   /* [4] rb bias b */
#define P_PROJ  213828   /* [30][64] proj */
#define P_TAU   215748   /* scalar */
#define P_TOTAL 215749

typedef unsigned short u16;
typedef unsigned int   u32;

__device__ __forceinline__ float u2f(u16 u) { return __uint_as_float(((u32)u) << 16); }
__device__ __forceinline__ u16  f2bf(float f) {  // round-to-nearest-even bf16
    u32 x = __float_as_uint(f);
    return (u16)((x + 0x7FFFu + ((x >> 16) & 1u)) >> 16);
}
// order-preserving float->uint encoding for atomicMax over signed floats
__device__ __forceinline__ u32  encf(float f) { u32 u = __float_as_uint(f); return (u & 0x80000000u) ? ~u : (u | 0x80000000u); }
__device__ __forceinline__ float decf(u32 u)  { return (u & 0x80000000u) ? __uint_as_float(u & 0x7FFFFFFFu) : __uint_as_float(~u); }

// ---------------- dtype detection (fp32 vs bf16 input tensors) ----------------
__global__ void k_detect(const u16* __restrict__ z, int* __restrict__ flag) {
    if (threadIdx.x == 0 && blockIdx.x == 0) {
        int bad = 0;
        for (int i = 0; i < 256; i += 2) {
            u16 u = z[i];
            int e = (u >> 7) & 0xFF;
            if (u != 0 && !(e >= 100 && e <= 140)) bad++;
        }
        *flag = (bad > 16) ? 1 : 0;   // 1 = inputs are fp32
    }
}

// ---------------- stage all small params to fp32 ----------------
__global__ __launch_bounds__(256) void k_cvt_params(
    const void* Wq, const void* Wk, const void* Wv,
    const void* bq, const void* bk, const void* bv,
    const void* Wo, const void* Wob, const void* bb, const void* proj,
    const void* taup, float* __restrict__ params, const int* __restrict__ flag)
{
    int i = blockIdx.x * 256 + threadIdx.x;
    if (i >= P_TOTAL) return;
    int f = *flag;
    if (i == P_TAU) {
        float v = f ? ((const float*)taup)[0] : u2f(((const u16*)taup)[0]);
        if (!(v > 1e-6f && v < 1e6f)) {
            float ff = ((const float*)taup)[0];
            v = (ff > 1e-6f && ff < 1e6f) ? ff : 0.25f;
        }
        params[i] = v;
        return;
    }
    const void* src; int j;
    if      (i < 65536)  { src = Wq;  j = i; }
    else if (i < 131072) { src = Wk;  j = i - 65536; }
    else if (i < 196608) { src = Wv;  j = i - 131072; }
    else if (i < 196864) { src = bq;  j = i - 196608; }
    else if (i < 197120) { src = bk;  j = i - 196864; }
    else if (i < 197376) { src = bv;  j = i - 197120; }
    else if (i < 213760) { src = Wo;  j = i - 197376; }
    else if (i < 213824) { src = Wob; j = i - 213760; }
    else if (i < 213828) { src = bb;  j = i - 213824; }
    else                 { src = proj; j = i - P_PROJ; }
    params[i] = f ? ((const float*)src)[j] : u2f(((const u16*)src)[j]);
}

// ---------------- degrees ----------------
__global__ __launch_bounds__(256) void k_deg(const int* __restrict__ ei, int* __restrict__ din, int* __restrict__ dout) {
    int e = blockIdx.x * 256 + threadIdx.x;
    if (e >= NE) return;
    atomicAdd(&dout[ei[e]], 1);
    atomicAdd(&din[ei[NE + e]], 1);
}

// ---------------- scan-free CSR offsets ----------------
__global__ __launch_bounds__(256) void k_off(const int* __restrict__ din, int* __restrict__ offn, int* __restrict__ counter) {
    __shared__ int s[256];
    __shared__ int base;
    int tid = threadIdx.x;
    int n = blockIdx.x * 256 + tid;
    int v = (n < NN) ? din[n] : 0;
    s[tid] = v;
    __syncthreads();
    for (int o = 1; o < 256; o <<= 1) {
        int t = (tid >= o) ? s[tid - o] : 0;
        __syncthreads();
        s[tid] += t;
        __syncthreads();
    }
    if (tid == 255) base = atomicAdd(counter, s[255]);
    __syncthreads();
    if (n < NN) offn[n] = base + s[tid] - v;
}

// fill CSR + precompute per-edge conv weight w = rsqrt(din[t]*dout[s])
__global__ __launch_bounds__(256) void k_fill(const int* __restrict__ ei, const int* __restrict__ offn,
                                              int* __restrict__ fill, int* __restrict__ csr,
                                              const int* __restrict__ din, const int* __restrict__ dout,
                                              float* __restrict__ wedge) {
    int e = blockIdx.x * 256 + threadIdx.x;
    if (e >= NE) return;
    int s = ei[e], t = ei[NE + e];
    int pos = offn[t] + atomicAdd(&fill[t], 1);
    csr[pos] = s;
    wedge[pos] = rsqrtf((float)din[t] * (float)dout[s]);
}

// ---------------- fused QKV GEMM + Performer feature epilogue ----------------
// grid (ceil(NN/64), 12): y 0..3 -> Q head y; y 4..7 -> K head y-4; y 8..11 -> V cols
// Round 9: As/Bs stride 68 (16B-aligned rows -> ds_read_b128 in inner loop,
// 2 LDS reads per 16 FMAs instead of 8); projL padded to stride 65 (kills the
// 4-way bank conflict on the epilogue proj dot); V output stored as bf16 V16.
__global__ __launch_bounds__(256) void k_gemm_feat(
    const void* __restrict__ zv, const float* __restrict__ params, const int* __restrict__ flag,
    u16* __restrict__ V16, float* __restrict__ qp, u16* __restrict__ qp16,
    float* __restrict__ dashK, float* __restrict__ diagK, u32* __restrict__ stab)
{
    __shared__ float smem[4352 + 1950];   // As(32x68)|Bs(32x68) -> tile(64x68); projL(30x65)
    __shared__ u32 smaxL;
    float* As    = smem;            // stride 68
    float* Bs    = smem + 2176;     // stride 68
    float* tile  = smem;            // 64 x 68, reuses As+Bs exactly
    float* projL = smem + 4352;     // stride 65

    const float* Wf = params + P_WF;
    const float* bf = params + P_BF;
    const int f32 = *flag;
    const int tid = threadIdx.x;
    const int bm = blockIdx.x * 64;
    const int bn = blockIdx.y * 64;

    if (bn < 512) {   // Q or K block: stage proj (padded stride 65)
        for (int i = tid; i < MF * DH; i += 256) projL[(i >> 6) * 65 + (i & 63)] = params[P_PROJ + i];
    }
    if (tid == 0) smaxL = 0u;

    const int lm = tid >> 2;          // 0..63
    const int lk = (tid & 3) * 8;     // 0,8,16,24
    const int tm = (tid >> 4) * 4;
    const int tn = (tid & 15) * 4;
    float acc[4][4] = {};

    for (int k0 = 0; k0 < 256; k0 += 32) {
        __syncthreads();
        int row = bm + lm;
        float e[8] = {0.f, 0.f, 0.f, 0.f, 0.f, 0.f, 0.f, 0.f};
        if (row < NN) {
            if (f32) {
                const float4* zp = (const float4*)((const float*)zv + (size_t)row * 256 + k0 + lk);
                float4 a = zp[0], c = zp[1];
                e[0] = a.x; e[1] = a.y; e[2] = a.z; e[3] = a.w;
                e[4] = c.x; e[5] = c.y; e[6] = c.z; e[7] = c.w;
            } else {
                uint4 av = *(const uint4*)((const u16*)zv + (size_t)row * 256 + k0 + lk);
                e[0] = __uint_as_float(av.x << 16); e[1] = __uint_as_float(av.x & 0xFFFF0000u);
                e[2] = __uint_as_float(av.y << 16); e[3] = __uint_as_float(av.y & 0xFFFF0000u);
                e[4] = __uint_as_float(av.z << 16); e[5] = __uint_as_float(av.z & 0xFFFF0000u);
                e[6] = __uint_as_float(av.w << 16); e[7] = __uint_as_float(av.w & 0xFFFF0000u);
            }
        }
        #pragma unroll
        for (int j = 0; j < 8; ++j) As[(lk + j) * 68 + lm] = e[j];
        const float4* wr = (const float4*)(Wf + (size_t)(bn + lm) * 256 + k0 + lk);
        float4 b0 = wr[0], b1 = wr[1];
        Bs[(lk + 0) * 68 + lm] = b0.x; Bs[(lk + 1) * 68 + lm] = b0.y;
        Bs[(lk + 2) * 68 + lm] = b0.z; Bs[(lk + 3) * 68 + lm] = b0.w;
        Bs[(lk + 4) * 68 + lm] = b1.x; Bs[(lk + 5) * 68 + lm] = b1.y;
        Bs[(lk + 6) * 68 + lm] = b1.z; Bs[(lk + 7) * 68 + lm] = b1.w;
        __syncthreads();
        #pragma unroll
        for (int kk = 0; kk < 32; ++kk) {
            float4 a4 = *(const float4*)(As + kk * 68 + tm);
            float4 b4 = *(const float4*)(Bs + kk * 68 + tn);
            acc[0][0] += a4.x * b4.x; acc[0][1] += a4.x * b4.y; acc[0][2] += a4.x * b4.z; acc[0][3] += a4.x * b4.w;
            acc[1][0] += a4.y * b4.x; acc[1][1] += a4.y * b4.y; acc[1][2] += a4.y * b4.z; acc[1][3] += a4.y * b4.w;
            acc[2][0] += a4.z * b4.x; acc[2][1] += a4.z * b4.y; acc[2][2] += a4.z * b4.z; acc[2][3] += a4.z * b4.w;
            acc[3][0] += a4.w * b4.x; acc[3][1] += a4.w * b4.y; acc[3][2] += a4.w * b4.z; acc[3][3] += a4.w * b4.w;
        }
    }
    __syncthreads();   // all As/Bs reads done; smem reusable as tile

    if (bn >= 512) {   // ---- V: bf16 store ----
        #pragma unroll
        for (int i = 0; i < 4; ++i) {
            int row = bm + tm + i;
            if (row < NN) {
                #pragma unroll
                for (int j = 0; j < 4; ++j)
                    V16[(size_t)row * 256 + (bn - 512) + tn + j] = f2bf(acc[i][j] + bf[bn + tn + j]);
            }
        }
        return;
    }

    // ---- Q/K: performer features on the 64x64 head tile ----
    float scale = DNRM * rsqrtf(params[P_TAU]);
    #pragma unroll
    for (int i = 0; i < 4; ++i)
        #pragma unroll
        for (int j = 0; j < 4; ++j)
            tile[(tm + i) * 68 + tn + j] = (acc[i][j] + bf[bn + tn + j]) * scale;
    __syncthreads();

    int r = tid >> 2, q = tid & 3;      // 4 lanes cooperate per row; same wave
    int n = bm + r;
    const float* trow = tile + r * 68;
    float dp = 0.f;
    #pragma unroll
    for (int d = q * 16; d < q * 16 + 16; ++d) dp += trow[d] * trow[d];
    dp += __shfl_xor(dp, 1);
    dp += __shfl_xor(dp, 2);
    float diag = dp * 0.5f;

    float dm[8];
    int nm = 0;
    float lmax = -3.0e38f;
    for (int m = q; m < MF; m += 4) {
        float s = 0.f;
        #pragma unroll
        for (int d = 0; d < DH; ++d) s += trow[d] * projL[m * 65 + d];
        dm[nm++] = s;
        lmax = fmaxf(lmax, s);
    }
    float mx = fmaxf(lmax, __shfl_xor(lmax, 1));
    mx = fmaxf(mx, __shfl_xor(mx, 2));

    if (bn < 256) {   // Q: row-local stab, write qp (fp32) + packed bf16 copy
        int h = blockIdx.y;
        if (n < NN) {
            float* o = qp + ((size_t)n * NH + h) * MF;
            u16* o16 = qp16 + ((size_t)n * NH + h) * 32;
            nm = 0;
            for (int m = q; m < MF; m += 4) {
                float v = RATIO * (expf(dm[nm++] - diag - mx) + 1e-6f);
                o[m] = v;
                o16[m] = f2bf(v);
            }
            if (q == 0) { o16[30] = 0; o16[31] = 0; }
        }
    } else {          // K: store dash/diag, global per-head max
        int h = blockIdx.y - 4;
        if (n < NN) {
            float* o = dashK + ((size_t)n * NH + h) * MF;
            nm = 0;
            for (int m = q; m < MF; m += 4) o[m] = dm[nm++];
            if (q == 0) {
                diagK[(size_t)n * NH + h] = diag;
                atomicMax(&smaxL, encf(mx));
            }
        }
        __syncthreads();
        if (tid == 0) atomicMax(&stab[h], smaxL);
    }
}

// ---------------- keys pass 2: kp in-place + kpsum + packed bf16 copy ----------------
__global__ __launch_bounds__(256) void k_kp(float* __restrict__ kp, const float* __restrict__ diagK,
                                            const u32* __restrict__ stab, float* __restrict__ kpsum,
                                            u16* __restrict__ kp16)
{
    __shared__ float part[NH * MF];
    __shared__ float stabf[4];
    int tid = threadIdx.x;
    if (tid < NH * MF) part[tid] = 0.f;
    if (tid >= 128 && tid < 132) stabf[tid - 128] = decf(stab[tid - 128]);
    __syncthreads();
    int base = blockIdx.x * 64 * MF;   // 64 rows/block, exact: 1875*64 = 120000
    for (int i = tid; i < 64 * MF; i += 256) {
        int row = blockIdx.x * 64 + i / MF;
        int m = i - (i / MF) * MF;
        int h = row & 3;
        float v = RATIO * (expf(kp[base + i] - diagK[row] - stabf[h]) + 1e-6f);
        kp[base + i] = v;
        kp16[(size_t)row * 32 + m] = f2bf(v);
        atomicAdd(&part[h * MF + m], v);
    }
    if (tid < 64) {
        int row = blockIdx.x * 64 + tid;
        kp16[(size_t)row * 32 + 30] = 0;
        kp16[(size_t)row * 32 + 31] = 0;
    }
    __syncthreads();
    if (tid < NH * MF) atomicAdd(&kpsum[tid], part[tid]);
}

// ---------------- attn_norm[n,h] = qp[n,h,:] . kpsum[h,:] ----------------
__global__ __launch_bounds__(256) void k_an(const float* __restrict__ qp, const float* __restrict__ kpsum,
                                            float* __restrict__ an)
{
    __shared__ float kps[NH * MF];
    int tid = threadIdx.x;
    if (tid < NH * MF) kps[tid] = kpsum[tid];
    __syncthreads();
    int idx = blockIdx.x * 256 + tid;
    if (idx >= NN * NH) return;
    int h = idx & 3;
    const float* q = qp + (size_t)idx * MF;
    float s = 0.f;
    #pragma unroll
    for (int m = 0; m < MF; ++m) s += q[m] * kps[h * MF + m];
    an[idx] = s;
}

// ---------------- kvs[h,k,m,d] & ksum[h,k,m] reduction over nodes ----------------
#define KVS_CHUNKS 25
#define KVS_NPB (NN / KVS_CHUNKS)    /* 1200 nodes per block */
#define KVS_TS 40                    /* nodes per LDS tile */
#define KVS_DZ 16                    /* d-slice width, grid.z = DH/KVS_DZ = 4 */
__global__ __launch_bounds__(320) void k_kvs(const float* __restrict__ kp, const void* __restrict__ gum,
                                             const u16* __restrict__ V16, const int* __restrict__ flag,
                                             float* __restrict__ kvs, float* __restrict__ ksum)
{
    __shared__ float kpL[KVS_TS][MF];
    __shared__ float egL[KVS_TS][KG];
    __shared__ float vL[KVS_TS][KVS_DZ];
    int tid = threadIdx.x;
    int h = blockIdx.y;
    int z = blockIdx.z;
    int d0 = z * KVS_DZ;
    int f32 = *flag;
    int n0 = blockIdx.x * KVS_NPB;
    int ki = tid / MF, mi = tid - ki * MF;   // valid for tid<300
    float acc[KVS_DZ] = {};
    float ksacc = 0.f;
    for (int t0 = 0; t0 < KVS_NPB; t0 += KVS_TS) {
        __syncthreads();
        for (int i = tid; i < KVS_TS * MF; i += 320) {          // kp tile (coalesced)
            int j = i / MF, m = i - j * MF;
            kpL[j][m] = kp[(size_t)(n0 + t0 + j) * (NH * MF) + h * MF + m];
        }
        for (int i = tid; i < KVS_TS * KG; i += 320) {          // exp(gumbel) tile
            int j = i / KG, k = i - j * KG;
            size_t gofs = (size_t)(n0 + t0 + j) * (NH * KG) + h * KG + k;
            float g = f32 ? ((const float*)gum)[gofs] : u2f(((const u16*)gum)[gofs]);
            egL[j][k] = expf(g);
        }
        for (int i = tid; i < KVS_TS * KVS_DZ; i += 320) {      // V d-slice tile (bf16)
            int j = i / KVS_DZ, dd = i - j * KVS_DZ;
            vL[j][dd] = u2f(V16[(size_t)(n0 + t0 + j) * 256 + h * 64 + d0 + dd]);
        }
        __syncthreads();
        if (tid < KG * MF) {
            for (int j = 0; j < KVS_TS; ++j) {
                float w = kpL[j][mi] * egL[j][ki];
                ksacc += w;
                #pragma unroll
                for (int dd = 0; dd < KVS_DZ; ++dd) acc[dd] += w * vL[j][dd];
            }
        }
    }
    if (tid < KG * MF) {
        int base = ((h * KG + ki) * MF + mi) * DH + d0;
        #pragma unroll
        for (int dd = 0; dd < KVS_DZ; ++dd) atomicAdd(&kvs[base + dd], acc[dd]);
        if (z == 0) atomicAdd(&ksum[(h * KG + ki) * MF + mi], ksacc);
    }
}

// ---------------- per-edge attention weights -> link loss partials ----------------
__global__ __launch_bounds__(256) void k_edge(const int* __restrict__ ei,
                                              const u16* __restrict__ qp16, const u16* __restrict__ kp16,
                                              const float* __restrict__ an,
                                              const int* __restrict__ din, float* __restrict__ lossp)
{
    __shared__ float ls[64];
    int tid = threadIdx.x;
    int eg = tid >> 2, h = tid & 3;
    int e = blockIdx.x * 64 + eg;           // grid = NE/64 exact
    int s = ei[e], t = ei[NE + e];
    const uint4* qv = (const uint4*)(qp16 + ((size_t)t * NH + h) * 32);
    const uint4* kv = (const uint4*)(kp16 + ((size_t)s * NH + h) * 32);
    float num = 0.f;
    #pragma unroll
    for (int c = 0; c < 4; ++c) {
        uint4 a = qv[c], b = kv[c];
        num += u2f((u16)(a.x & 0xFFFF)) * u2f((u16)(b.x & 0xFFFF))
             + u2f((u16)(a.x >> 16))    * u2f((u16)(b.x >> 16))
             + u2f((u16)(a.y & 0xFFFF)) * u2f((u16)(b.y & 0xFFFF))
             + u2f((u16)(a.y >> 16))    * u2f((u16)(b.y >> 16))
             + u2f((u16)(a.z & 0xFFFF)) * u2f((u16)(b.z & 0xFFFF))
             + u2f((u16)(a.z >> 16))    * u2f((u16)(b.z >> 16))
             + u2f((u16)(a.w & 0xFFFF)) * u2f((u16)(b.w & 0xFFFF))
             + u2f((u16)(a.w >> 16))    * u2f((u16)(b.w >> 16));
    }
    float term = logf(num / an[(size_t)t * NH + h]);
    term += __shfl_xor(term, 1);
    term += __shfl_xor(term, 2);
    if (h == 0) ls[eg] = term / (float)din[t];
    __syncthreads();
    if (tid < 64) {
        float v = ls[tid];
        #pragma unroll
        for (int o = 32; o > 0; o >>= 1) v += __shfl_xor(v, o);
        if (tid == 0) atomicAdd(&lossp[blockIdx.x & 1023], v);
    }
}

// ---------------- attention readout: 16 nodes/block, kvs staged in LDS ----------------
#define AT_NT 16
__global__ __launch_bounds__(256) void k_attn(
    const float* __restrict__ qp, const float* __restrict__ kvs, const float* __restrict__ ksum,
    u16* __restrict__ zatt)
{
    __shared__ float qpTf[NH * 484];          // plane h: [m][j] stride 16, plane pad->484
    __shared__ float kvL[NH * 1924];          // plane h: [m][d] stride 64, plane pad->1924
    __shared__ float rdenL[AT_NT * NH * KG];  // [j][h][k]
    __shared__ float ksL[NH * KG * MF];
    int tid = threadIdx.x;
    int n0 = blockIdx.x * AT_NT;

    for (int i = tid; i < AT_NT * NH * MF; i += 256) {   // qp -> transposed LDS
        int j = i / (NH * MF); int r = i - j * (NH * MF);
        int h = r / MF; int m = r - h * MF;
        qpTf[h * 484 + m * 16 + j] = qp[(size_t)(n0 + j) * (NH * MF) + r];
    }
    for (int i = tid; i < NH * KG * MF; i += 256) ksL[i] = ksum[i];
    __syncthreads();
    for (int i = tid; i < AT_NT * NH * KG; i += 256) {   // rden[j][h][k] = 1/(qp.ksum)
        int j = i / (NH * KG); int r = i - j * (NH * KG);
        int h = r / KG; int k = r - h * KG;
        float s = 0.f;
        #pragma unroll
        for (int m = 0; m < MF; ++m) s += qpTf[h * 484 + m * 16 + j] * ksL[(h * KG + k) * MF + m];
        rdenL[i] = 1.0f / s;
    }

    const int h  = tid >> 6;
    const int jg = (tid >> 4) & 3;
    const int dg = tid & 15;
    float acc[4][4] = {};
    for (int k = 0; k < KG; ++k) {
        __syncthreads();
        for (int i = tid; i < NH * MF * DH; i += 256) {  // stage kvs[:,k,:,:]
            int hh = i / (MF * DH); int r = i - hh * (MF * DH);
            kvL[hh * 1924 + r] = kvs[((size_t)(hh * KG + k) * MF) * DH + r];
        }
        __syncthreads();
        float ps[4][4] = {};
        const float* qb = qpTf + h * 484 + jg * 4;
        const float* kb = kvL + h * 1924 + dg * 4;
        #pragma unroll
        for (int m = 0; m < MF; ++m) {
            float4 a = *(const float4*)(qb + m * 16);
            float4 b = *(const float4*)(kb + m * 64);
            ps[0][0] += a.x * b.x; ps[0][1] += a.x * b.y; ps[0][2] += a.x * b.z; ps[0][3] += a.x * b.w;
            ps[1][0] += a.y * b.x; ps[1][1] += a.y * b.y; ps[1][2] += a.y * b.z; ps[1][3] += a.y * b.w;
            ps[2][0] += a.z * b.x; ps[2][1] += a.z * b.y; ps[2][2] += a.z * b.z; ps[2][3] += a.z * b.w;
            ps[3][0] += a.w * b.x; ps[3][1] += a.w * b.y; ps[3][2] += a.w * b.z; ps[3][3] += a.w * b.w;
        }
        #pragma unroll
        for (int j4 = 0; j4 < 4; ++j4) {
            float rd = rdenL[(jg * 4 + j4) * (NH * KG) + h * KG + k];
            #pragma unroll
            for (int d4 = 0; d4 < 4; ++d4) acc[j4][d4] += ps[j4][d4] * rd;
        }
    }
    #pragma unroll
    for (int j4 = 0; j4 < 4; ++j4) {
        int n = n0 + jg * 4 + j4;
        #pragma unroll
        for (int d4 = 0; d4 < 4; ++d4)
            zatt[(size_t)n * 256 + h * 64 + dg * 4 + d4] = f2bf(acc[j4][d4] * (1.0f / KG));
    }
}

// ---------------- conv gather + zatt add + Wo projection ----------------
// Round 9: csr/wedge staged via LDS (2 loads/edge instead of 512 redundantly
// issued per block); V gathered as bf16 (half the bytes of round-8 fp32).
__global__ __launch_bounds__(256) void k_conv(
    const u16* __restrict__ zatt, const u16* __restrict__ V16,
    const int* __restrict__ csr, const float* __restrict__ wedge,
    const int* __restrict__ offn, const int* __restrict__ din,
    const float* __restrict__ params, float* __restrict__ out)
{
    __shared__ float sL[256];
    __shared__ int   sIdx[128];
    __shared__ float sW[128];
    __shared__ float sigb[4];
    int n = blockIdx.x, tid = threadIdx.x;
    if (tid < 4) sigb[tid] = 1.f / (1.f + expf(-params[P_BBF + tid]));
    int h = tid >> 6;
    int dn = din[n], o0 = offn[n];
    float cacc = 0.f;
    for (int t0 = 0; t0 < dn; t0 += 128) {
        int cnt = min(128, dn - t0);
        __syncthreads();
        if (tid < cnt) { sIdx[tid] = csr[o0 + t0 + tid]; sW[tid] = wedge[o0 + t0 + tid]; }
        __syncthreads();
        int j = 0;
        for (; j + 4 <= cnt; j += 4) {
            float v0 = u2f(V16[(size_t)sIdx[j + 0] * 256 + tid]);
            float v1 = u2f(V16[(size_t)sIdx[j + 1] * 256 + tid]);
            float v2 = u2f(V16[(size_t)sIdx[j + 2] * 256 + tid]);
            float v3 = u2f(V16[(size_t)sIdx[j + 3] * 256 + tid]);
            cacc += sW[j] * v0 + sW[j + 1] * v1 + sW[j + 2] * v2 + sW[j + 3] * v3;
        }
        for (; j < cnt; ++j) cacc += sW[j] * u2f(V16[(size_t)sIdx[j] * 256 + tid]);
    }
    __syncthreads();
    sL[tid] = u2f(zatt[(size_t)n * 256 + tid]) + sigb[h] * cacc;
    __syncthreads();
    if (tid < 64) {
        float o = params[P_WOBF + tid];
        const float4* wr = (const float4*)(params + P_WOF + (size_t)tid * 256);
        #pragma unroll 8
        for (int c4 = 0; c4 < 64; ++c4) {
            float4 u = wr[c4];
            const float* sp = sL + c4 * 4;
            o += u.x * sp[0] + u.y * sp[1] + u.z * sp[2] + u.w * sp[3];
        }
        out[(size_t)n * 64 + tid] = o;   // fp32 output, per reference dtype
    }
}

// ---------------- loss finalize ----------------
__global__ __launch_bounds__(256) void k_loss(const float* __restrict__ lossp, float* __restrict__ out) {
    __shared__ float s[256];
    int tid = threadIdx.x;
    float v = 0.f;
    for (int i = tid; i < 1024; i += 256) v += lossp[i];
    s[tid] = v;
    __syncthreads();
    for (int o = 128; o > 0; o >>= 1) {
        if (tid < o) s[tid] += s[tid + o];
        __syncthreads();
    }
    if (tid == 0) out[(size_t)NN * 64] = s[0] / (float)(NE * NH);   // fp32 output
}

extern "C" void kernel_launch(void* const* d_in, const int* in_sizes, int n_in,
                              void* d_out, int out_size, void* d_ws, size_t ws_size,
                              hipStream_t stream)
{
    const void* z    = d_in[0];
    const int*  ei   = (const int*)d_in[1];
    const void* taup = d_in[2];
    const void* gum  = d_in[3];
    const void* proj = d_in[4];
    const void* Wq   = d_in[5];
    const void* bq   = d_in[6];
    const void* Wk   = d_in[7];
    const void* bk   = d_in[8];
    const void* Wv   = d_in[9];
    const void* bv   = d_in[10];
    const void* Wo   = d_in[11];
    const void* Wob  = d_in[12];
    const void* bb   = d_in[13];
    float* out = (float*)d_out;

    // ---- workspace carve-up (fp32 units), total ~67 MB ----
    u16*   V16    = (u16*)d_ws;                    //  7,680,000 u16 : [N,256] bf16 V
    float* qpb    = (float*)d_ws + 3840000;        //  3,600,000 : [N,H,M]
    float* kpb    = qpb + (size_t)NN * NH * MF;    //  3,600,000 : dashK then kp in-place
    float* diagK  = kpb + (size_t)NN * NH * MF;    //    120,000
    float* anb    = diagK + (size_t)NN * NH;       //    120,000
    // zatt (bf16 [N,256] = 7.68M u16 = 3.84M fp32 slots) reuses kpb+diagK+anb,
    // all dead after k_edge. k_attn runs after k_edge/k_kvs -> safe.
    u16*   zatt   = (u16*)kpb;
    int*   csr    = (int*)(anb + (size_t)NN * NH); //    480,000
    int*   offn   = csr + NE;                      //     30,000
    float* params = (float*)(offn + NN);           //    215,749 (+pad to 215,752)
    // ---- zeroed accumulator region ----
    float* kvs    = params + 215752;               //     76,800 : [H,K,M,D]
    float* ksum   = kvs + NH * KG * MF * DH;       //      1,200 : [H,K,M]
    float* kpsum  = ksum + NH * KG * MF;           //        120 : [H,M]
    int*   din    = (int*)(kpsum + NH * MF);       //     30,000
    int*   doutd  = din + NN;                      //     30,000
    int*   fill   = doutd + NN;                    //     30,000
    int*   counter = fill + NN;                    //          4
    u32*   stab   = (u32*)(counter + 4);           //          4
    float* lossp  = (float*)(stab + 4);            //      1,024
    int*   flag   = (int*)(lossp + 1024);          //          4
    float* wedge  = (float*)(flag + 4);            //    480,000 (not zeroed; fully written)
    u16*   qp16   = (u16*)(wedge + NE);            //  3,840,000 u16 : [N,H,32] bf16 qp
    u16*   kp16   = qp16 + (size_t)NN * NH * 32;   //  3,840,000 u16 : [N,H,32] bf16 kp
    size_t zero_bytes = (size_t)((char*)(flag + 4) - (char*)kvs);

    hipMemsetAsync(kvs, 0, zero_bytes, stream);

    k_detect<<<dim3(1), dim3(64), 0, stream>>>((const u16*)z, flag);
    k_cvt_params<<<dim3((P_TOTAL + 255) / 256), dim3(256), 0, stream>>>(
        Wq, Wk, Wv, bq, bk, bv, Wo, Wob, bb, proj, taup, params, flag);

    k_deg <<<dim3((NE + 255) / 256), dim3(256), 0, stream>>>(ei, din, doutd);
    k_off <<<dim3((NN + 255) / 256), dim3(256), 0, stream>>>(din, offn, counter);
    k_fill<<<dim3((NE + 255) / 256), dim3(256), 0, stream>>>(ei, offn, fill, csr, din, doutd, wedge);
    k_gemm_feat<<<dim3((NN + 63) / 64, 12), dim3(256), 0, stream>>>(
        z, params, flag, V16, qpb, qp16, kpb, diagK, stab);
    k_kp  <<<dim3(NN * NH / 64), dim3(256), 0, stream>>>(kpb, diagK, stab, kpsum, kp16);
    k_an  <<<dim3((NN * NH + 255) / 256), dim3(256), 0, stream>>>(qpb, kpsum, anb);
    k_kvs <<<dim3(KVS_CHUNKS, NH, DH / KVS_DZ), dim3(320), 0, stream>>>(kpb, gum, V16, flag, kvs, ksum);
    k_edge<<<dim3(NE / 64), dim3(256), 0, stream>>>(ei, qp16, kp16, anb, din, lossp);
    // zatt overwrites kpb/diagK/anb from here on (stream-ordered after their last readers)
    k_attn<<<dim3(NN / AT_NT), dim3(256), 0, stream>>>(qpb, kvs, ksum, zatt);
    k_conv<<<dim3(NN), dim3(256), 0, stream>>>(zatt, V16, csr, wedge, offn, din, params, out);
    k_loss<<<dim3(1), dim3(256), 0, stream>>>(lossp, out);
}